// Round 1
// baseline (599.598 us; speedup 1.0000x reference)
//
#include <hip/hip_runtime.h>
#include <cstdint>

typedef __bf16 bf16;
typedef __attribute__((ext_vector_type(8))) __bf16 bf16x8;
typedef __attribute__((ext_vector_type(4))) __bf16 bf16x4;
typedef __attribute__((ext_vector_type(4))) float f32x4;

#define AS1C(p) ((const __attribute__((address_space(1))) void*)(p))
#define AS3(p)  ((__attribute__((address_space(3))) void*)(p))

__device__ __forceinline__ float gelu_exact(float v) {
    return 0.5f * v * (1.0f + erff(v * 0.7071067811865476f));
}

// ---------------------------------------------------------------------------
// Weight transpose + fp32->bf16 convert: w [K][N] fp32 -> wt [N][K] bf16
// grid: (N/64, K/64), block 256
// ---------------------------------------------------------------------------
__global__ __launch_bounds__(256, 1) void wtrans_kernel(
    const float* __restrict__ w, bf16* __restrict__ wt, int K, int N)
{
    __shared__ float tile[64][65];
    const int k0 = blockIdx.y * 64, n0 = blockIdx.x * 64;
    const int tid = threadIdx.x;
    {
        const int kl = tid >> 2, nc = (tid & 3) * 16;
        #pragma unroll
        for (int i = 0; i < 4; ++i) {
            const float4 v = *(const float4*)&w[(size_t)(k0 + kl) * N + n0 + nc + i * 4];
            tile[kl][nc + i * 4 + 0] = v.x;
            tile[kl][nc + i * 4 + 1] = v.y;
            tile[kl][nc + i * 4 + 2] = v.z;
            tile[kl][nc + i * 4 + 3] = v.w;
        }
    }
    __syncthreads();
    {
        const int nl = tid >> 2, kc = (tid & 3) * 16;
        #pragma unroll
        for (int i = 0; i < 4; ++i) {
            bf16x4 o4;
            o4[0] = (bf16)tile[kc + i * 4 + 0][nl];
            o4[1] = (bf16)tile[kc + i * 4 + 1][nl];
            o4[2] = (bf16)tile[kc + i * 4 + 2][nl];
            o4[3] = (bf16)tile[kc + i * 4 + 3][nl];
            *(bf16x4*)&wt[(size_t)(n0 + nl) * K + k0 + kc + i * 4] = o4;
        }
    }
}

// ---------------------------------------------------------------------------
// Concatenate 3 bias vectors of 1024 into one 3072 fp32 buffer. grid 12x256
// ---------------------------------------------------------------------------
__global__ void bias3_kernel(const float* __restrict__ a, const float* __restrict__ b,
                             const float* __restrict__ c, float* __restrict__ o)
{
    const int i = blockIdx.x * 256 + threadIdx.x;
    o[i] = (i < 1024) ? a[i] : (i < 2048 ? b[i - 1024] : c[i - 2048]);
}

// ---------------------------------------------------------------------------
// LayerNorm over rows of 1024 fp32 -> bf16. grid 8192 x 256
// ---------------------------------------------------------------------------
__global__ __launch_bounds__(256, 1) void ln_kernel(
    const float* __restrict__ x, const float* __restrict__ gw,
    const float* __restrict__ bw, bf16* __restrict__ out)
{
    const int row = blockIdx.x, tid = threadIdx.x;
    const float4 v = *(const float4*)&x[(size_t)row * 1024 + tid * 4];
    float s = v.x + v.y + v.z + v.w;
    float q = v.x * v.x + v.y * v.y + v.z * v.z + v.w * v.w;
    #pragma unroll
    for (int off = 32; off > 0; off >>= 1) {
        s += __shfl_xor(s, off);
        q += __shfl_xor(q, off);
    }
    __shared__ float red[8];
    if ((tid & 63) == 0) { red[tid >> 6] = s; red[4 + (tid >> 6)] = q; }
    __syncthreads();
    s = red[0] + red[1] + red[2] + red[3];
    q = red[4] + red[5] + red[6] + red[7];
    const float mu = s * (1.f / 1024.f);
    const float rs = rsqrtf(q * (1.f / 1024.f) - mu * mu + 1e-5f);
    const float4 gg = *(const float4*)&gw[tid * 4];
    const float4 bb = *(const float4*)&bw[tid * 4];
    bf16x4 o4;
    o4[0] = (bf16)((v.x - mu) * rs * gg.x + bb.x);
    o4[1] = (bf16)((v.y - mu) * rs * gg.y + bb.y);
    o4[2] = (bf16)((v.z - mu) * rs * gg.z + bb.z);
    o4[3] = (bf16)((v.w - mu) * rs * gg.w + bb.w);
    *(bf16x4*)&out[(size_t)row * 1024 + tid * 4] = o4;
}

// ---------------------------------------------------------------------------
// Tiled MFMA GEMM: C[M][N] = A[M][K] @ BT[N][K]^T + bias, with fused epilogue.
// EPI: 0 = bias -> bf16 out
//      1 = bias + res(f32) -> f32 out
//      2 = gelu(bias+acc) -> bf16 out
//      3 = gelu(bias+acc) + res(f32) -> f32 out
// block 256 (4 waves 2x2), tile 128x128, BK=32. grid (N/128, M/128)
// ---------------------------------------------------------------------------
template<int EPI>
__global__ __launch_bounds__(256, 1) void gemm_kernel(
    const bf16* __restrict__ A, const bf16* __restrict__ BT,
    const float* __restrict__ bias, const float* __restrict__ res,
    void* __restrict__ out, int M, int N, int K)
{
    __shared__ __attribute__((aligned(16))) bf16 lA[128 * 32];
    __shared__ __attribute__((aligned(16))) bf16 lB[128 * 32];
    const int tid = threadIdx.x;
    const int lane = tid & 63;
    const int wid = tid >> 6;
    const int wr = wid >> 1, wc = wid & 1;
    const int j = lane & 15, g = lane >> 4;
    const int bm = blockIdx.y * 128, bn = blockIdx.x * 128;

    f32x4 acc[4][4] = {};

    for (int k0 = 0; k0 < K; k0 += 32) {
        #pragma unroll
        for (int L = 0; L < 2; ++L) {
            const int c = L * 256 + tid;
            const bf16* ga = A + (size_t)(bm + (c >> 2)) * K + k0 + ((c & 3) << 3);
            __builtin_amdgcn_global_load_lds(AS1C(ga), AS3(lA + (L * 256 + wid * 64) * 8), 16, 0, 0);
            const bf16* gb = BT + (size_t)(bn + (c >> 2)) * K + k0 + ((c & 3) << 3);
            __builtin_amdgcn_global_load_lds(AS1C(gb), AS3(lB + (L * 256 + wid * 64) * 8), 16, 0, 0);
        }
        __syncthreads();
        bf16x8 af[4], bfr[4];
        #pragma unroll
        for (int m = 0; m < 4; ++m)
            af[m] = *(const bf16x8*)&lA[(wr * 64 + m * 16 + j) * 32 + g * 8];
        #pragma unroll
        for (int n = 0; n < 4; ++n)
            bfr[n] = *(const bf16x8*)&lB[(wc * 64 + n * 16 + j) * 32 + g * 8];
        #pragma unroll
        for (int m = 0; m < 4; ++m)
            #pragma unroll
            for (int n = 0; n < 4; ++n)
                acc[m][n] = __builtin_amdgcn_mfma_f32_16x16x32_bf16(af[m], bfr[n], acc[m][n], 0, 0, 0);
        __syncthreads();
    }

    const int row0 = bm + wr * 64;
    const int col0 = bn + wc * 64;
    #pragma unroll
    for (int n = 0; n < 4; ++n) {
        const int col = col0 + n * 16 + j;
        const float bs = bias[col];
        #pragma unroll
        for (int m = 0; m < 4; ++m) {
            #pragma unroll
            for (int r = 0; r < 4; ++r) {
                const int row = row0 + m * 16 + g * 4 + r;
                float v = acc[m][n][r] + bs;
                if constexpr (EPI == 2 || EPI == 3) v = gelu_exact(v);
                if constexpr (EPI == 1 || EPI == 3) {
                    v += res[(size_t)row * N + col];
                    ((float*)out)[(size_t)row * N + col] = v;
                } else {
                    ((bf16*)out)[(size_t)row * N + col] = (bf16)v;
                }
            }
        }
    }
}

// ---------------------------------------------------------------------------
// Flash attention: qkv [8192][3072] bf16 (q|k|v interleaved per row),
// out attn [8192][1024] bf16 (layout [b, i, h, d]).
// grid (16 q-tiles, 128 b*h), block 256 (4 waves x 16 q-rows). scale = 1/32.
// ---------------------------------------------------------------------------
__global__ __launch_bounds__(256, 1) void attn_kernel(
    const bf16* __restrict__ qkv, bf16* __restrict__ attn)
{
    const int tid = threadIdx.x;
    const int lane = tid & 63, wid = tid >> 6;
    const int j = lane & 15, g = lane >> 4;
    const int b = blockIdx.y >> 4, h = blockIdx.y & 15;
    const int q0 = blockIdx.x * 64 + wid * 16;

    const bf16* Qp = qkv + (size_t)b * 1024 * 3072 + h * 64;
    const bf16* Kp = Qp + 1024;
    const bf16* Vp = Qp + 2048;

    __shared__ __attribute__((aligned(16))) bf16 vT[64 * 32];       // [d][key]
    __shared__ __attribute__((aligned(16))) bf16 pS[4][16 * 32];    // per-wave P

    const bf16x8 qf0 = *(const bf16x8*)&Qp[(size_t)(q0 + j) * 3072 + g * 8];
    const bf16x8 qf1 = *(const bf16x8*)&Qp[(size_t)(q0 + j) * 3072 + 32 + g * 8];

    f32x4 o[4] = {};
    float mrun[4] = {-1e30f, -1e30f, -1e30f, -1e30f};
    float lrun[4] = {0.f, 0.f, 0.f, 0.f};
    const f32x4 zero = {0.f, 0.f, 0.f, 0.f};

    for (int c = 0; c < 32; ++c) {
        const int key0 = c * 32;
        // V chunk -> regs (32 keys x 64 d)
        const int vkey = tid >> 3, vd0 = (tid & 7) * 8;
        const bf16x8 vv = *(const bf16x8*)&Vp[(size_t)(key0 + vkey) * 3072 + vd0];
        // S = Q K^T for two 16-key tiles
        f32x4 s[2];
        #pragma unroll
        for (int t = 0; t < 2; ++t) {
            const bf16x8 kf0 = *(const bf16x8*)&Kp[(size_t)(key0 + t * 16 + j) * 3072 + g * 8];
            const bf16x8 kf1 = *(const bf16x8*)&Kp[(size_t)(key0 + t * 16 + j) * 3072 + 32 + g * 8];
            s[t] = __builtin_amdgcn_mfma_f32_16x16x32_bf16(qf0, kf0, zero, 0, 0, 0);
            s[t] = __builtin_amdgcn_mfma_f32_16x16x32_bf16(qf1, kf1, s[t], 0, 0, 0);
        }
        __syncthreads();   // previous-iteration vT/pS reads complete
        #pragma unroll
        for (int i = 0; i < 8; ++i)
            vT[(vd0 + i) * 32 + vkey] = vv[i];
        // online softmax (rows 4g+r, cols j within 16-lane groups)
        float p[2][4];
        #pragma unroll
        for (int t = 0; t < 2; ++t)
            #pragma unroll
            for (int r = 0; r < 4; ++r) s[t][r] *= 0.03125f;
        #pragma unroll
        for (int r = 0; r < 4; ++r) {
            float cur = fmaxf(s[0][r], s[1][r]);
            cur = fmaxf(cur, __shfl_xor(cur, 1));
            cur = fmaxf(cur, __shfl_xor(cur, 2));
            cur = fmaxf(cur, __shfl_xor(cur, 4));
            cur = fmaxf(cur, __shfl_xor(cur, 8));
            const float mnew = fmaxf(mrun[r], cur);
            const float alpha = __expf(mrun[r] - mnew);
            p[0][r] = __expf(s[0][r] - mnew);
            p[1][r] = __expf(s[1][r] - mnew);
            float rsum = p[0][r] + p[1][r];
            rsum += __shfl_xor(rsum, 1);
            rsum += __shfl_xor(rsum, 2);
            rsum += __shfl_xor(rsum, 4);
            rsum += __shfl_xor(rsum, 8);
            lrun[r] = lrun[r] * alpha + rsum;
            mrun[r] = mnew;
            #pragma unroll
            for (int dt = 0; dt < 4; ++dt) o[dt][r] *= alpha;
        }
        // P -> LDS in A-fragment layout
        #pragma unroll
        for (int t = 0; t < 2; ++t)
            #pragma unroll
            for (int r = 0; r < 4; ++r)
                pS[wid][(g * 4 + r) * 32 + t * 16 + j] = (bf16)p[t][r];
        __syncthreads();   // vT + pS ready
        // O += P V
        const bf16x8 pa = *(const bf16x8*)&pS[wid][j * 32 + g * 8];
        #pragma unroll
        for (int dt = 0; dt < 4; ++dt) {
            const bf16x8 vb = *(const bf16x8*)&vT[(dt * 16 + j) * 32 + g * 8];
            o[dt] = __builtin_amdgcn_mfma_f32_16x16x32_bf16(pa, vb, o[dt], 0, 0, 0);
        }
    }
    #pragma unroll
    for (int dt = 0; dt < 4; ++dt)
        #pragma unroll
        for (int r = 0; r < 4; ++r)
            attn[(size_t)(b * 1024 + q0 + g * 4 + r) * 1024 + h * 64 + dt * 16 + j] =
                (bf16)(o[dt][r] / lrun[r]);
}

// ---------------------------------------------------------------------------
extern "C" void kernel_launch(void* const* d_in, const int* in_sizes, int n_in,
                              void* d_out, int out_size, void* d_ws, size_t ws_size,
                              hipStream_t stream)
{
    const float* x    = (const float*)d_in[0];
    const float* ln1g = (const float*)d_in[1];
    const float* ln1b = (const float*)d_in[2];
    const float* wq   = (const float*)d_in[3];
    const float* bq   = (const float*)d_in[4];
    const float* wk   = (const float*)d_in[5];
    const float* bk   = (const float*)d_in[6];
    const float* wv   = (const float*)d_in[7];
    const float* bv   = (const float*)d_in[8];
    const float* wo   = (const float*)d_in[9];
    const float* bo   = (const float*)d_in[10];
    const float* ln2g = (const float*)d_in[11];
    const float* ln2b = (const float*)d_in[12];
    const float* w1   = (const float*)d_in[13];
    const float* b1   = (const float*)d_in[14];
    const float* w2   = (const float*)d_in[15];
    const float* b2   = (const float*)d_in[16];

    char* ws = (char*)d_ws;
    bf16* wqkvT = (bf16*)ws;  ws += (size_t)3072 * 1024 * 2;
    bf16* woT   = (bf16*)ws;  ws += (size_t)1024 * 1024 * 2;
    bf16* w1T   = (bf16*)ws;  ws += (size_t)4096 * 1024 * 2;
    bf16* w2T   = (bf16*)ws;  ws += (size_t)1024 * 4096 * 2;
    float* bqkv = (float*)ws; ws += (size_t)3072 * 4;
    bf16* h     = (bf16*)ws;  ws += (size_t)8192 * 1024 * 2;   // LN1 out, reused for LN2 out
    bf16* qkv   = (bf16*)ws;  ws += (size_t)8192 * 3072 * 2;
    bf16* attn  = (bf16*)ws;  ws += (size_t)8192 * 1024 * 2;
    float* outf = (float*)ws; ws += (size_t)8192 * 1024 * 4;
    bf16* m1    = (bf16*)ws;  ws += (size_t)8192 * 4096 * 2;

    // weight transposes (fp32 -> bf16, [K][N] -> [N][K])
    wtrans_kernel<<<dim3(16, 16), 256, 0, stream>>>(wq, wqkvT,                   1024, 1024);
    wtrans_kernel<<<dim3(16, 16), 256, 0, stream>>>(wk, wqkvT + 1024 * 1024,     1024, 1024);
    wtrans_kernel<<<dim3(16, 16), 256, 0, stream>>>(wv, wqkvT + 2 * 1024 * 1024, 1024, 1024);
    wtrans_kernel<<<dim3(16, 16), 256, 0, stream>>>(wo, woT, 1024, 1024);
    wtrans_kernel<<<dim3(64, 16), 256, 0, stream>>>(w1, w1T, 1024, 4096);
    wtrans_kernel<<<dim3(16, 64), 256, 0, stream>>>(w2, w2T, 4096, 1024);
    bias3_kernel<<<12, 256, 0, stream>>>(bq, bk, bv, bqkv);

    // LN1: x -> h (bf16)
    ln_kernel<<<8192, 256, 0, stream>>>(x, ln1g, ln1b, h);
    // QKV projection: h @ [wq|wk|wv] -> qkv [8192][3072]
    gemm_kernel<0><<<dim3(24, 64), 256, 0, stream>>>(h, wqkvT, bqkv, nullptr, qkv, 8192, 3072, 1024);
    // attention
    attn_kernel<<<dim3(16, 128), 256, 0, stream>>>(qkv, attn);
    // O projection + bias + residual(x) -> outf (fp32)
    gemm_kernel<1><<<dim3(8, 64), 256, 0, stream>>>(attn, woT, bo, x, outf, 8192, 1024, 1024);
    // LN2: outf -> h (bf16, reuse)
    ln_kernel<<<8192, 256, 0, stream>>>(outf, ln2g, ln2b, h);
    // MLP1: gelu(h @ w1 + b1) -> m1 [8192][4096]
    gemm_kernel<2><<<dim3(32, 64), 256, 0, stream>>>(h, w1T, b1, nullptr, m1, 8192, 4096, 1024);
    // MLP2: gelu(m1 @ w2 + b2) + outf -> d_out (fp32)
    gemm_kernel<3><<<dim3(8, 64), 256, 0, stream>>>(m1, w2T, b2, outf, (float*)d_out, 8192, 1024, 4096);
}

// Round 2
// 562.557 us; speedup vs baseline: 1.0658x; 1.0658x over previous
//
#include <hip/hip_runtime.h>
#include <cstdint>

typedef __bf16 bf16;
typedef __attribute__((ext_vector_type(8))) __bf16 bf16x8;
typedef __attribute__((ext_vector_type(4))) __bf16 bf16x4;
typedef __attribute__((ext_vector_type(4))) float f32x4;
typedef __attribute__((ext_vector_type(8))) unsigned short u16x8;

#define AS1C(p) ((const __attribute__((address_space(1))) void*)(p))
#define AS3(p)  ((__attribute__((address_space(3))) void*)(p))

__device__ __forceinline__ float gelu_exact(float v) {
    return 0.5f * v * (1.0f + erff(v * 0.7071067811865476f));
}

// ---------------------------------------------------------------------------
// Weight transpose + fp32->bf16 convert: w [K][N] fp32 -> wt [N][K] bf16
// grid: (N/64, K/64), block 256
// ---------------------------------------------------------------------------
__global__ __launch_bounds__(256, 1) void wtrans_kernel(
    const float* __restrict__ w, bf16* __restrict__ wt, int K, int N)
{
    __shared__ float tile[64][65];
    const int k0 = blockIdx.y * 64, n0 = blockIdx.x * 64;
    const int tid = threadIdx.x;
    {
        const int kl = tid >> 2, nc = (tid & 3) * 16;
        #pragma unroll
        for (int i = 0; i < 4; ++i) {
            const float4 v = *(const float4*)&w[(size_t)(k0 + kl) * N + n0 + nc + i * 4];
            tile[kl][nc + i * 4 + 0] = v.x;
            tile[kl][nc + i * 4 + 1] = v.y;
            tile[kl][nc + i * 4 + 2] = v.z;
            tile[kl][nc + i * 4 + 3] = v.w;
        }
    }
    __syncthreads();
    {
        const int nl = tid >> 2, kc = (tid & 3) * 16;
        #pragma unroll
        for (int i = 0; i < 4; ++i) {
            bf16x4 o4;
            o4[0] = (bf16)tile[kc + i * 4 + 0][nl];
            o4[1] = (bf16)tile[kc + i * 4 + 1][nl];
            o4[2] = (bf16)tile[kc + i * 4 + 2][nl];
            o4[3] = (bf16)tile[kc + i * 4 + 3][nl];
            *(bf16x4*)&wt[(size_t)(n0 + nl) * K + k0 + kc + i * 4] = o4;
        }
    }
}

// ---------------------------------------------------------------------------
// Concatenate 3 bias vectors of 1024 into one 3072 fp32 buffer. grid 12x256
// ---------------------------------------------------------------------------
__global__ void bias3_kernel(const float* __restrict__ a, const float* __restrict__ b,
                             const float* __restrict__ c, float* __restrict__ o)
{
    const int i = blockIdx.x * 256 + threadIdx.x;
    o[i] = (i < 1024) ? a[i] : (i < 2048 ? b[i - 1024] : c[i - 2048]);
}

// ---------------------------------------------------------------------------
// LayerNorm over rows of 1024 fp32 -> bf16. grid 8192 x 256
// ---------------------------------------------------------------------------
__global__ __launch_bounds__(256, 1) void ln_kernel(
    const float* __restrict__ x, const float* __restrict__ gw,
    const float* __restrict__ bw, bf16* __restrict__ out)
{
    const int row = blockIdx.x, tid = threadIdx.x;
    const float4 v = *(const float4*)&x[(size_t)row * 1024 + tid * 4];
    float s = v.x + v.y + v.z + v.w;
    float q = v.x * v.x + v.y * v.y + v.z * v.z + v.w * v.w;
    #pragma unroll
    for (int off = 32; off > 0; off >>= 1) {
        s += __shfl_xor(s, off);
        q += __shfl_xor(q, off);
    }
    __shared__ float red[8];
    if ((tid & 63) == 0) { red[tid >> 6] = s; red[4 + (tid >> 6)] = q; }
    __syncthreads();
    s = red[0] + red[1] + red[2] + red[3];
    q = red[4] + red[5] + red[6] + red[7];
    const float mu = s * (1.f / 1024.f);
    const float rs = rsqrtf(q * (1.f / 1024.f) - mu * mu + 1e-5f);
    const float4 gg = *(const float4*)&gw[tid * 4];
    const float4 bb = *(const float4*)&bw[tid * 4];
    bf16x4 o4;
    o4[0] = (bf16)((v.x - mu) * rs * gg.x + bb.x);
    o4[1] = (bf16)((v.y - mu) * rs * gg.y + bb.y);
    o4[2] = (bf16)((v.z - mu) * rs * gg.z + bb.z);
    o4[3] = (bf16)((v.w - mu) * rs * gg.w + bb.w);
    *(bf16x4*)&out[(size_t)row * 1024 + tid * 4] = o4;
}

// ---------------------------------------------------------------------------
// Tiled MFMA GEMM: C[M][N] = A[M][K] @ BT[N][K]^T + bias, with fused epilogue.
// EPI: 0 = bias -> bf16 out
//      1 = bias + res(f32) -> f32 out
//      2 = gelu(bias+acc) -> bf16 out
//      3 = gelu(bias+acc) + res(f32) -> f32 out
// block 256 (4 waves 2x2), tile 128x128, BK=32. grid (N/128, M/128)
// ---------------------------------------------------------------------------
template<int EPI>
__global__ __launch_bounds__(256, 1) void gemm_kernel(
    const bf16* __restrict__ A, const bf16* __restrict__ BT,
    const float* __restrict__ bias, const float* __restrict__ res,
    void* __restrict__ out, int M, int N, int K)
{
    __shared__ __attribute__((aligned(16))) bf16 lA[128 * 32];
    __shared__ __attribute__((aligned(16))) bf16 lB[128 * 32];
    const int tid = threadIdx.x;
    const int lane = tid & 63;
    const int wid = tid >> 6;
    const int wr = wid >> 1, wc = wid & 1;
    const int j = lane & 15, g = lane >> 4;
    const int bm = blockIdx.y * 128, bn = blockIdx.x * 128;

    f32x4 acc[4][4] = {};

    for (int k0 = 0; k0 < K; k0 += 32) {
        #pragma unroll
        for (int L = 0; L < 2; ++L) {
            const int c = L * 256 + tid;
            const bf16* ga = A + (size_t)(bm + (c >> 2)) * K + k0 + ((c & 3) << 3);
            __builtin_amdgcn_global_load_lds(AS1C(ga), AS3(lA + (L * 256 + wid * 64) * 8), 16, 0, 0);
            const bf16* gb = BT + (size_t)(bn + (c >> 2)) * K + k0 + ((c & 3) << 3);
            __builtin_amdgcn_global_load_lds(AS1C(gb), AS3(lB + (L * 256 + wid * 64) * 8), 16, 0, 0);
        }
        __syncthreads();
        bf16x8 af[4], bfr[4];
        #pragma unroll
        for (int m = 0; m < 4; ++m)
            af[m] = *(const bf16x8*)&lA[(wr * 64 + m * 16 + j) * 32 + g * 8];
        #pragma unroll
        for (int n = 0; n < 4; ++n)
            bfr[n] = *(const bf16x8*)&lB[(wc * 64 + n * 16 + j) * 32 + g * 8];
        #pragma unroll
        for (int m = 0; m < 4; ++m)
            #pragma unroll
            for (int n = 0; n < 4; ++n)
                acc[m][n] = __builtin_amdgcn_mfma_f32_16x16x32_bf16(af[m], bfr[n], acc[m][n], 0, 0, 0);
        __syncthreads();
    }

    const int row0 = bm + wr * 64;
    const int col0 = bn + wc * 64;
    #pragma unroll
    for (int n = 0; n < 4; ++n) {
        const int col = col0 + n * 16 + j;
        const float bs = bias[col];
        #pragma unroll
        for (int m = 0; m < 4; ++m) {
            #pragma unroll
            for (int r = 0; r < 4; ++r) {
                const int row = row0 + m * 16 + g * 4 + r;
                float v = acc[m][n][r] + bs;
                if constexpr (EPI == 2 || EPI == 3) v = gelu_exact(v);
                if constexpr (EPI == 1 || EPI == 3) {
                    v += res[(size_t)row * N + col];
                    ((float*)out)[(size_t)row * N + col] = v;
                } else {
                    ((bf16*)out)[(size_t)row * N + col] = (bf16)v;
                }
            }
        }
    }
}

// ---------------------------------------------------------------------------
// Flash attention v2: swapped QK^T with permuted K-tiles so P is born in the
// PV A-fragment layout (no P LDS, no P shuffles). KVBLK=64, double-buffered
// V^T in LDS ([64][72] u32-packed, conflict-free), 1 barrier/iter.
// qkv [8192][3072] bf16 (q|k|v per row), out attn [8192][1024] bf16 [b,i,h,d].
// grid (16, 128), block 256 (4 waves x 16 q-rows). scale 1/32 folded into Q.
// ---------------------------------------------------------------------------
__global__ __launch_bounds__(256, 1) void attn_kernel(
    const bf16* __restrict__ qkv, bf16* __restrict__ attn)
{
    const int tid = threadIdx.x;
    const int lane = tid & 63, wid = tid >> 6;
    const int j = lane & 15, g = lane >> 4;

    // XCD swizzle: put the 16 q-tiles of one (b,h) on the same XCD
    const int lin = blockIdx.x + blockIdx.y * 16;
    const int virt = (lin & 7) * 256 + (lin >> 3);
    const int bh = virt >> 4, qt = virt & 15;
    const int b = bh >> 4, h = bh & 15;
    const int q0 = qt * 64 + wid * 16;

    const bf16* Qp = qkv + (size_t)b * 1024 * 3072 + h * 64;
    const bf16* Kp = Qp + 1024;
    const bf16* Vp = Qp + 2048;

    // V^T double buffer: [buf][d=64][key-pairs=32 u32] (row stride 36 u32 = pad)
    __shared__ __attribute__((aligned(16))) uint32_t vTu[2][64][36];

    // ---- stage V block 0 ----
    const int kp = (tid & 31) * 2;          // key pair base
    const int d0 = (tid >> 5) * 8;          // 8 d-values per thread
    {
        const u16x8 r0 = *(const u16x8*)&Vp[(size_t)kp * 3072 + d0];
        const u16x8 r1 = *(const u16x8*)&Vp[(size_t)(kp + 1) * 3072 + d0];
        #pragma unroll
        for (int i = 0; i < 8; ++i)
            vTu[0][d0 + i][tid & 31] = (uint32_t)r0[i] | ((uint32_t)r1[i] << 16);
    }

    // ---- Q fragments (scaled by 1/32, exact in bf16) ----
    bf16x8 qf0 = *(const bf16x8*)&Qp[(size_t)(q0 + j) * 3072 + g * 8];
    bf16x8 qf1 = *(const bf16x8*)&Qp[(size_t)(q0 + j) * 3072 + 32 + g * 8];
    #pragma unroll
    for (int e = 0; e < 8; ++e) {
        qf0[e] = (bf16)((float)qf0[e] * 0.03125f);
        qf1[e] = (bf16)((float)qf1[e] * 0.03125f);
    }

    const int jperm = (j >> 2) * 8 + (j & 3);   // K-row permutation base

    f32x4 o[4] = {};
    float mrun = -1e30f, lsum = 0.f;
    const f32x4 zero = {0.f, 0.f, 0.f, 0.f};

    __syncthreads();

    for (int c = 0; c < 16; ++c) {
        const int key0 = c * 64;
        // issue V loads for block c+1 early (hide HBM under QK^T)
        u16x8 r0, r1;
        if (c + 1 < 16) {
            const size_t vb = (size_t)(key0 + 64 + kp) * 3072 + d0;
            r0 = *(const u16x8*)&Vp[vb];
            r1 = *(const u16x8*)&Vp[vb + 3072];
        }

        // ---- QK^T (swapped: A = K rows, B = Q). Tile t covers keys
        //      (t>>1)*32 + g*8 + (t&1)*4 + r  for the output regs. ----
        f32x4 s[4];
        #pragma unroll
        for (int t = 0; t < 4; ++t) {
            const int key = key0 + (t >> 1) * 32 + jperm + (t & 1) * 4;
            const bf16x8 kf0 = *(const bf16x8*)&Kp[(size_t)key * 3072 + g * 8];
            const bf16x8 kf1 = *(const bf16x8*)&Kp[(size_t)key * 3072 + 32 + g * 8];
            s[t] = __builtin_amdgcn_mfma_f32_16x16x32_bf16(kf0, qf0, zero, 0, 0, 0);
            s[t] = __builtin_amdgcn_mfma_f32_16x16x32_bf16(kf1, qf1, s[t], 0, 0, 0);
        }

        // ---- online softmax, row = q0+j entirely in-lane (+2 shfl) ----
        float cur = fmaxf(fmaxf(s[0][0], s[0][1]), fmaxf(s[0][2], s[0][3]));
        #pragma unroll
        for (int t = 1; t < 4; ++t) {
            cur = fmaxf(cur, fmaxf(fmaxf(s[t][0], s[t][1]), fmaxf(s[t][2], s[t][3])));
        }
        cur = fmaxf(cur, __shfl_xor(cur, 16));
        cur = fmaxf(cur, __shfl_xor(cur, 32));

        if (!__all(cur - mrun <= 8.0f)) {       // defer-max (THR=8)
            const float mnew = fmaxf(mrun, cur);
            const float alpha = __expf(mrun - mnew);
            float al[4];
            #pragma unroll
            for (int r = 0; r < 4; ++r) al[r] = __shfl(alpha, g * 4 + r);
            #pragma unroll
            for (int dt = 0; dt < 4; ++dt)
                #pragma unroll
                for (int r = 0; r < 4; ++r) o[dt][r] *= al[r];
            lsum *= alpha;
            mrun = mnew;
        }
        float ps = 0.f;
        #pragma unroll
        for (int t = 0; t < 4; ++t)
            #pragma unroll
            for (int r = 0; r < 4; ++r) {
                const float p = __expf(s[t][r] - mrun);
                s[t][r] = p;
                ps += p;
            }
        lsum += ps;

        // P -> bf16 A-fragments (already in PV layout, zero redistribution)
        bf16x8 pa0, pa1;
        #pragma unroll
        for (int r = 0; r < 4; ++r) {
            pa0[r]     = (bf16)s[0][r];
            pa0[4 + r] = (bf16)s[1][r];
            pa1[r]     = (bf16)s[2][r];
            pa1[4 + r] = (bf16)s[3][r];
        }

        // write V block c+1 into the other buffer
        if (c + 1 < 16) {
            #pragma unroll
            for (int i = 0; i < 8; ++i)
                vTu[(c + 1) & 1][d0 + i][tid & 31] = (uint32_t)r0[i] | ((uint32_t)r1[i] << 16);
        }

        // ---- O += P V  (B = V^T rows from LDS) ----
        #pragma unroll
        for (int dt = 0; dt < 4; ++dt) {
            const bf16* vrow = (const bf16*)&vTu[c & 1][dt * 16 + j][0];
            const bf16x8 vb0 = *(const bf16x8*)(vrow + g * 8);
            const bf16x8 vb1 = *(const bf16x8*)(vrow + 32 + g * 8);
            o[dt] = __builtin_amdgcn_mfma_f32_16x16x32_bf16(pa0, vb0, o[dt], 0, 0, 0);
            o[dt] = __builtin_amdgcn_mfma_f32_16x16x32_bf16(pa1, vb1, o[dt], 0, 0, 0);
        }
        __syncthreads();
    }

    // ---- epilogue: l reduce (2 shfl) + per-row fetch (4 shfl) ----
    lsum += __shfl_xor(lsum, 16);
    lsum += __shfl_xor(lsum, 32);
    float inv[4];
    #pragma unroll
    for (int r = 0; r < 4; ++r) inv[r] = 1.0f / __shfl(lsum, g * 4 + r);
    #pragma unroll
    for (int dt = 0; dt < 4; ++dt)
        #pragma unroll
        for (int r = 0; r < 4; ++r)
            attn[(size_t)(b * 1024 + q0 + g * 4 + r) * 1024 + h * 64 + dt * 16 + j] =
                (bf16)(o[dt][r] * inv[r]);
}

// ---------------------------------------------------------------------------
extern "C" void kernel_launch(void* const* d_in, const int* in_sizes, int n_in,
                              void* d_out, int out_size, void* d_ws, size_t ws_size,
                              hipStream_t stream)
{
    const float* x    = (const float*)d_in[0];
    const float* ln1g = (const float*)d_in[1];
    const float* ln1b = (const float*)d_in[2];
    const float* wq   = (const float*)d_in[3];
    const float* bq   = (const float*)d_in[4];
    const float* wk   = (const float*)d_in[5];
    const float* bk   = (const float*)d_in[6];
    const float* wv   = (const float*)d_in[7];
    const float* bv   = (const float*)d_in[8];
    const float* wo   = (const float*)d_in[9];
    const float* bo   = (const float*)d_in[10];
    const float* ln2g = (const float*)d_in[11];
    const float* ln2b = (const float*)d_in[12];
    const float* w1   = (const float*)d_in[13];
    const float* b1   = (const float*)d_in[14];
    const float* w2   = (const float*)d_in[15];
    const float* b2   = (const float*)d_in[16];

    char* ws = (char*)d_ws;
    bf16* wqkvT = (bf16*)ws;  ws += (size_t)3072 * 1024 * 2;
    bf16* woT   = (bf16*)ws;  ws += (size_t)1024 * 1024 * 2;
    bf16* w1T   = (bf16*)ws;  ws += (size_t)4096 * 1024 * 2;
    bf16* w2T   = (bf16*)ws;  ws += (size_t)1024 * 4096 * 2;
    float* bqkv = (float*)ws; ws += (size_t)3072 * 4;
    bf16* h     = (bf16*)ws;  ws += (size_t)8192 * 1024 * 2;   // LN1 out, reused for LN2 out
    bf16* qkv   = (bf16*)ws;  ws += (size_t)8192 * 3072 * 2;
    bf16* attn  = (bf16*)ws;  ws += (size_t)8192 * 1024 * 2;
    float* outf = (float*)ws; ws += (size_t)8192 * 1024 * 4;
    bf16* m1    = (bf16*)ws;  ws += (size_t)8192 * 4096 * 2;

    // weight transposes (fp32 -> bf16, [K][N] -> [N][K])
    wtrans_kernel<<<dim3(16, 16), 256, 0, stream>>>(wq, wqkvT,                   1024, 1024);
    wtrans_kernel<<<dim3(16, 16), 256, 0, stream>>>(wk, wqkvT + 1024 * 1024,     1024, 1024);
    wtrans_kernel<<<dim3(16, 16), 256, 0, stream>>>(wv, wqkvT + 2 * 1024 * 1024, 1024, 1024);
    wtrans_kernel<<<dim3(16, 16), 256, 0, stream>>>(wo, woT, 1024, 1024);
    wtrans_kernel<<<dim3(64, 16), 256, 0, stream>>>(w1, w1T, 1024, 4096);
    wtrans_kernel<<<dim3(16, 64), 256, 0, stream>>>(w2, w2T, 4096, 1024);
    bias3_kernel<<<12, 256, 0, stream>>>(bq, bk, bv, bqkv);

    // LN1: x -> h (bf16)
    ln_kernel<<<8192, 256, 0, stream>>>(x, ln1g, ln1b, h);
    // QKV projection: h @ [wq|wk|wv] -> qkv [8192][3072]
    gemm_kernel<0><<<dim3(24, 64), 256, 0, stream>>>(h, wqkvT, bqkv, nullptr, qkv, 8192, 3072, 1024);
    // attention
    attn_kernel<<<dim3(16, 128), 256, 0, stream>>>(qkv, attn);
    // O projection + bias + residual(x) -> outf (fp32)
    gemm_kernel<1><<<dim3(8, 64), 256, 0, stream>>>(attn, woT, bo, x, outf, 8192, 1024, 1024);
    // LN2: outf -> h (bf16, reuse)
    ln_kernel<<<8192, 256, 0, stream>>>(outf, ln2g, ln2b, h);
    // MLP1: gelu(h @ w1 + b1) -> m1 [8192][4096]
    gemm_kernel<2><<<dim3(32, 64), 256, 0, stream>>>(h, w1T, b1, nullptr, m1, 8192, 4096, 1024);
    // MLP2: gelu(m1 @ w2 + b2) + outf -> d_out (fp32)
    gemm_kernel<3><<<dim3(8, 64), 256, 0, stream>>>(m1, w2T, b2, outf, (float*)d_out, 8192, 1024, 4096);
}

// Round 3
// 559.622 us; speedup vs baseline: 1.0714x; 1.0052x over previous
//
#include <hip/hip_runtime.h>
#include <cstdint>

typedef __bf16 bf16;
typedef __attribute__((ext_vector_type(8))) __bf16 bf16x8;
typedef __attribute__((ext_vector_type(4))) __bf16 bf16x4;
typedef __attribute__((ext_vector_type(4))) float f32x4;
typedef __attribute__((ext_vector_type(8))) unsigned short u16x8;

#define AS1C(p) ((const __attribute__((address_space(1))) void*)(p))
#define AS3(p)  ((__attribute__((address_space(3))) void*)(p))

__device__ __forceinline__ float gelu_exact(float v) {
    return 0.5f * v * (1.0f + erff(v * 0.7071067811865476f));
}

// ---------------------------------------------------------------------------
// Weight transpose + fp32->bf16 convert: w [K][N] fp32 -> wt [N][K] bf16
// ---------------------------------------------------------------------------
__global__ __launch_bounds__(256, 1) void wtrans_kernel(
    const float* __restrict__ w, bf16* __restrict__ wt, int K, int N)
{
    __shared__ float tile[64][65];
    const int k0 = blockIdx.y * 64, n0 = blockIdx.x * 64;
    const int tid = threadIdx.x;
    {
        const int kl = tid >> 2, nc = (tid & 3) * 16;
        #pragma unroll
        for (int i = 0; i < 4; ++i) {
            const float4 v = *(const float4*)&w[(size_t)(k0 + kl) * N + n0 + nc + i * 4];
            tile[kl][nc + i * 4 + 0] = v.x;
            tile[kl][nc + i * 4 + 1] = v.y;
            tile[kl][nc + i * 4 + 2] = v.z;
            tile[kl][nc + i * 4 + 3] = v.w;
        }
    }
    __syncthreads();
    {
        const int nl = tid >> 2, kc = (tid & 3) * 16;
        #pragma unroll
        for (int i = 0; i < 4; ++i) {
            bf16x4 o4;
            o4[0] = (bf16)tile[kc + i * 4 + 0][nl];
            o4[1] = (bf16)tile[kc + i * 4 + 1][nl];
            o4[2] = (bf16)tile[kc + i * 4 + 2][nl];
            o4[3] = (bf16)tile[kc + i * 4 + 3][nl];
            *(bf16x4*)&wt[(size_t)(n0 + nl) * K + k0 + kc + i * 4] = o4;
        }
    }
}

__global__ void bias3_kernel(const float* __restrict__ a, const float* __restrict__ b,
                             const float* __restrict__ c, float* __restrict__ o)
{
    const int i = blockIdx.x * 256 + threadIdx.x;
    o[i] = (i < 1024) ? a[i] : (i < 2048 ? b[i - 1024] : c[i - 2048]);
}

// ---------------------------------------------------------------------------
// LayerNorm over rows of 1024 fp32 -> bf16. grid 8192 x 256
// ---------------------------------------------------------------------------
__global__ __launch_bounds__(256, 1) void ln_kernel(
    const float* __restrict__ x, const float* __restrict__ gw,
    const float* __restrict__ bw, bf16* __restrict__ out)
{
    const int row = blockIdx.x, tid = threadIdx.x;
    const float4 v = *(const float4*)&x[(size_t)row * 1024 + tid * 4];
    float s = v.x + v.y + v.z + v.w;
    float q = v.x * v.x + v.y * v.y + v.z * v.z + v.w * v.w;
    #pragma unroll
    for (int off = 32; off > 0; off >>= 1) {
        s += __shfl_xor(s, off);
        q += __shfl_xor(q, off);
    }
    __shared__ float red[8];
    if ((tid & 63) == 0) { red[tid >> 6] = s; red[4 + (tid >> 6)] = q; }
    __syncthreads();
    s = red[0] + red[1] + red[2] + red[3];
    q = red[4] + red[5] + red[6] + red[7];
    const float mu = s * (1.f / 1024.f);
    const float rs = rsqrtf(q * (1.f / 1024.f) - mu * mu + 1e-5f);
    const float4 gg = *(const float4*)&gw[tid * 4];
    const float4 bb = *(const float4*)&bw[tid * 4];
    bf16x4 o4;
    o4[0] = (bf16)((v.x - mu) * rs * gg.x + bb.x);
    o4[1] = (bf16)((v.y - mu) * rs * gg.y + bb.y);
    o4[2] = (bf16)((v.z - mu) * rs * gg.z + bb.z);
    o4[3] = (bf16)((v.w - mu) * rs * gg.w + bb.w);
    *(bf16x4*)&out[(size_t)row * 1024 + tid * 4] = o4;
}

// ---------------------------------------------------------------------------
// 8-phase 256xBN GEMM (HK-derived template, plain HIP).
// C[M][N] = A[M][K] @ BT[N][K]^T + bias, fused epilogue (EPI as before).
// 512 threads = 8 waves. BK=64. st_16x32 LDS swizzle (T2) via pre-swizzled
// global source (linear global_load_lds dest) + swizzled ds_read.
// BN=256: 2 LDS buffers (128KB), depth-1 prefetch, vmcnt(0)/tile.
// BN=128: 3 LDS buffers (144KB), depth-2 prefetch, counted vmcnt(6) (T4).
// Per phase: ds_read frags | stage | barrier | lgkmcnt(0) | setprio(1) MFMA
// cluster setprio(0) | [vmcnt] | barrier.   (T3+T5)
// ---------------------------------------------------------------------------
template<int BCH>
__device__ __forceinline__ void stage_tile(
    const bf16* __restrict__ A, const bf16* __restrict__ BT, int K,
    int bm, int bn, int k0, char* buf, int wid, int lanep)
{
    const int rsub = lanep >> 3, ksub = (lanep & 7) * 8;
    #pragma unroll
    for (int c = 0; c < 4; ++c) {
        const bf16* src = A + (size_t)(bm + c * 64 + wid * 8 + rsub) * K + k0 + ksub;
        __builtin_amdgcn_global_load_lds(AS1C(src), AS3(buf + (c * 8 + wid) * 1024), 16, 0, 0);
    }
    #pragma unroll
    for (int c = 0; c < BCH; ++c) {
        const bf16* src = BT + (size_t)(bn + c * 64 + wid * 8 + rsub) * K + k0 + ksub;
        __builtin_amdgcn_global_load_lds(AS1C(src), AS3(buf + 32768 + (c * 8 + wid) * 1024), 16, 0, 0);
    }
}

template<int EPI, int BN>
__global__ __launch_bounds__(512, 2) void gemm8p_kernel(
    const bf16* __restrict__ A, const bf16* __restrict__ BT,
    const float* __restrict__ bias, const float* __restrict__ res,
    void* __restrict__ out, int M, int N, int K)
{
    constexpr int PWM = (BN == 256) ? 128 : 64;   // per-wave M rows
    constexpr int PWN = 64;
    constexpr int MF = PWM / 16;                   // 8 or 4
    constexpr int NF = 4;
    constexpr int MFH = MF / 2;                    // 4 or 2
    constexpr int NFH = 2;
    constexpr int BCH = BN / 64;                   // B stage chunks: 4 or 2
    constexpr int BUFB = (256 + BN) * 128;         // bytes per buffer
    constexpr int NBUF = (BN == 256) ? 2 : 3;
    extern __shared__ char lds[];

    const int tid = threadIdx.x;
    const int lane = tid & 63, wid = tid >> 6;
    const int wr = (BN == 256) ? (wid >> 2) : (wid >> 1);
    const int wc = (BN == 256) ? (wid & 3) : (wid & 1);
    const int j = lane & 15, g = lane >> 4;
    const int lanep = lane ^ ((lane >> 4) & 2);    // inverse st_16x32 on source

    // XCD-aware block swizzle (all grids are multiples of 8)
    const int nbn = N / BN;
    const int nwg = (M / 256) * nbn;
    const int bid = blockIdx.x;
    const int wg = (bid & 7) * (nwg >> 3) + (bid >> 3);
    const int bm = (wg / nbn) * 256;
    const int bn = (wg % nbn) * BN;

    f32x4 acc[MF][NF] = {};
    const int NT = K >> 6;

    stage_tile<BCH>(A, BT, K, bm, bn, 0, lds, wid, lanep);
    if constexpr (NBUF == 3) {
        stage_tile<BCH>(A, BT, K, bm, bn, 64, lds + BUFB, wid, lanep);
        asm volatile("s_waitcnt vmcnt(6)" ::: "memory");
    } else {
        asm volatile("s_waitcnt vmcnt(0)" ::: "memory");
    }
    __builtin_amdgcn_s_barrier();

    for (int t = 0; t < NT; ++t) {
        char* buf = lds + ((NBUF == 2) ? (t & 1) : (t % 3)) * BUFB;
        #pragma unroll
        for (int qm = 0; qm < 2; ++qm) {
            bf16x8 af[MFH][2];
            #pragma unroll
            for (int mf = 0; mf < MFH; ++mf)
                #pragma unroll
                for (int ks = 0; ks < 2; ++ks) {
                    const int R = wr * PWM + (qm * MFH + mf) * 16 + j;
                    uint32_t lb = (uint32_t)(R * 128 + ks * 64 + g * 16);
                    lb ^= (uint32_t)(R & 4) << 3;
                    af[mf][ks] = *(const bf16x8*)(buf + lb);
                }
            #pragma unroll
            for (int qn = 0; qn < 2; ++qn) {
                bf16x8 bfr[NFH][2];
                #pragma unroll
                for (int nf = 0; nf < NFH; ++nf)
                    #pragma unroll
                    for (int ks = 0; ks < 2; ++ks) {
                        const int R = wc * PWN + (qn * NFH + nf) * 16 + j;
                        uint32_t lb = (uint32_t)(R * 128 + ks * 64 + g * 16);
                        lb ^= (uint32_t)(R & 4) << 3;
                        bfr[nf][ks] = *(const bf16x8*)(buf + 32768 + lb);
                    }
                if (qm == 0 && qn == 0) {
                    if constexpr (NBUF == 2) {
                        if (t + 1 < NT)
                            stage_tile<BCH>(A, BT, K, bm, bn, (t + 1) << 6,
                                            lds + ((t + 1) & 1) * BUFB, wid, lanep);
                    } else {
                        if (t + 2 < NT)
                            stage_tile<BCH>(A, BT, K, bm, bn, (t + 2) << 6,
                                            lds + ((t + 2) % 3) * BUFB, wid, lanep);
                    }
                }
                __builtin_amdgcn_s_barrier();
                asm volatile("s_waitcnt lgkmcnt(0)" ::: "memory");
                __builtin_amdgcn_sched_barrier(0);
                __builtin_amdgcn_s_setprio(1);
                #pragma unroll
                for (int mf = 0; mf < MFH; ++mf)
                    #pragma unroll
                    for (int nf = 0; nf < NFH; ++nf)
                        #pragma unroll
                        for (int ks = 0; ks < 2; ++ks)
                            acc[qm * MFH + mf][qn * NFH + nf] =
                                __builtin_amdgcn_mfma_f32_16x16x32_bf16(
                                    af[mf][ks], bfr[nf][ks],
                                    acc[qm * MFH + mf][qn * NFH + nf], 0, 0, 0);
                __builtin_amdgcn_s_setprio(0);
                if (qm == 1 && qn == 1) {
                    if constexpr (NBUF == 2) {
                        asm volatile("s_waitcnt vmcnt(0)" ::: "memory");
                    } else {
                        if (t + 2 < NT) asm volatile("s_waitcnt vmcnt(6)" ::: "memory");
                        else            asm volatile("s_waitcnt vmcnt(0)" ::: "memory");
                    }
                }
                __builtin_amdgcn_s_barrier();
            }
        }
    }

    const int row0 = bm + wr * PWM;
    const int col0 = bn + wc * PWN;
    #pragma unroll
    for (int nf = 0; nf < NF; ++nf) {
        const int col = col0 + nf * 16 + j;
        const float bs = bias[col];
        #pragma unroll
        for (int mf = 0; mf < MF; ++mf) {
            #pragma unroll
            for (int r = 0; r < 4; ++r) {
                const int row = row0 + mf * 16 + g * 4 + r;
                float v = acc[mf][nf][r] + bs;
                if constexpr (EPI == 2 || EPI == 3) v = gelu_exact(v);
                if constexpr (EPI == 1 || EPI == 3) {
                    v += res[(size_t)row * N + col];
                    ((float*)out)[(size_t)row * N + col] = v;
                } else {
                    ((bf16*)out)[(size_t)row * N + col] = (bf16)v;
                }
            }
        }
    }
}

// ---------------------------------------------------------------------------
// Flash attention (unchanged from round 2)
// ---------------------------------------------------------------------------
__global__ __launch_bounds__(256, 1) void attn_kernel(
    const bf16* __restrict__ qkv, bf16* __restrict__ attn)
{
    const int tid = threadIdx.x;
    const int lane = tid & 63, wid = tid >> 6;
    const int j = lane & 15, g = lane >> 4;

    const int lin = blockIdx.x + blockIdx.y * 16;
    const int virt = (lin & 7) * 256 + (lin >> 3);
    const int bh = virt >> 4, qt = virt & 15;
    const int b = bh >> 4, h = bh & 15;
    const int q0 = qt * 64 + wid * 16;

    const bf16* Qp = qkv + (size_t)b * 1024 * 3072 + h * 64;
    const bf16* Kp = Qp + 1024;
    const bf16* Vp = Qp + 2048;

    __shared__ __attribute__((aligned(16))) uint32_t vTu[2][64][36];

    const int kp = (tid & 31) * 2;
    const int d0 = (tid >> 5) * 8;
    {
        const u16x8 r0 = *(const u16x8*)&Vp[(size_t)kp * 3072 + d0];
        const u16x8 r1 = *(const u16x8*)&Vp[(size_t)(kp + 1) * 3072 + d0];
        #pragma unroll
        for (int i = 0; i < 8; ++i)
            vTu[0][d0 + i][tid & 31] = (uint32_t)r0[i] | ((uint32_t)r1[i] << 16);
    }

    bf16x8 qf0 = *(const bf16x8*)&Qp[(size_t)(q0 + j) * 3072 + g * 8];
    bf16x8 qf1 = *(const bf16x8*)&Qp[(size_t)(q0 + j) * 3072 + 32 + g * 8];
    #pragma unroll
    for (int e = 0; e < 8; ++e) {
        qf0[e] = (bf16)((float)qf0[e] * 0.03125f);
        qf1[e] = (bf16)((float)qf1[e] * 0.03125f);
    }

    const int jperm = (j >> 2) * 8 + (j & 3);

    f32x4 o[4] = {};
    float mrun = -1e30f, lsum = 0.f;
    const f32x4 zero = {0.f, 0.f, 0.f, 0.f};

    __syncthreads();

    for (int c = 0; c < 16; ++c) {
        const int key0 = c * 64;
        u16x8 r0, r1;
        if (c + 1 < 16) {
            const size_t vb = (size_t)(key0 + 64 + kp) * 3072 + d0;
            r0 = *(const u16x8*)&Vp[vb];
            r1 = *(const u16x8*)&Vp[vb + 3072];
        }

        f32x4 s[4];
        #pragma unroll
        for (int t = 0; t < 4; ++t) {
            const int key = key0 + (t >> 1) * 32 + jperm + (t & 1) * 4;
            const bf16x8 kf0 = *(const bf16x8*)&Kp[(size_t)key * 3072 + g * 8];
            const bf16x8 kf1 = *(const bf16x8*)&Kp[(size_t)key * 3072 + 32 + g * 8];
            s[t] = __builtin_amdgcn_mfma_f32_16x16x32_bf16(kf0, qf0, zero, 0, 0, 0);
            s[t] = __builtin_amdgcn_mfma_f32_16x16x32_bf16(kf1, qf1, s[t], 0, 0, 0);
        }

        float cur = fmaxf(fmaxf(s[0][0], s[0][1]), fmaxf(s[0][2], s[0][3]));
        #pragma unroll
        for (int t = 1; t < 4; ++t)
            cur = fmaxf(cur, fmaxf(fmaxf(s[t][0], s[t][1]), fmaxf(s[t][2], s[t][3])));
        cur = fmaxf(cur, __shfl_xor(cur, 16));
        cur = fmaxf(cur, __shfl_xor(cur, 32));

        if (!__all(cur - mrun <= 8.0f)) {
            const float mnew = fmaxf(mrun, cur);
            const float alpha = __expf(mrun - mnew);
            float al[4];
            #pragma unroll
            for (int r = 0; r < 4; ++r) al[r] = __shfl(alpha, g * 4 + r);
            #pragma unroll
            for (int dt = 0; dt < 4; ++dt)
                #pragma unroll
                for (int r = 0; r < 4; ++r) o[dt][r] *= al[r];
            lsum *= alpha;
            mrun = mnew;
        }
        float ps = 0.f;
        #pragma unroll
        for (int t = 0; t < 4; ++t)
            #pragma unroll
            for (int r = 0; r < 4; ++r) {
                const float p = __expf(s[t][r] - mrun);
                s[t][r] = p;
                ps += p;
            }
        lsum += ps;

        bf16x8 pa0, pa1;
        #pragma unroll
        for (int r = 0; r < 4; ++r) {
            pa0[r]     = (bf16)s[0][r];
            pa0[4 + r] = (bf16)s[1][r];
            pa1[r]     = (bf16)s[2][r];
            pa1[4 + r] = (bf16)s[3][r];
        }

        if (c + 1 < 16) {
            #pragma unroll
            for (int i = 0; i < 8; ++i)
                vTu[(c + 1) & 1][d0 + i][tid & 31] = (uint32_t)r0[i] | ((uint32_t)r1[i] << 16);
        }

        #pragma unroll
        for (int dt = 0; dt < 4; ++dt) {
            const bf16* vrow = (const bf16*)&vTu[c & 1][dt * 16 + j][0];
            const bf16x8 vb0 = *(const bf16x8*)(vrow + g * 8);
            const bf16x8 vb1 = *(const bf16x8*)(vrow + 32 + g * 8);
            o[dt] = __builtin_amdgcn_mfma_f32_16x16x32_bf16(pa0, vb0, o[dt], 0, 0, 0);
            o[dt] = __builtin_amdgcn_mfma_f32_16x16x32_bf16(pa1, vb1, o[dt], 0, 0, 0);
        }
        __syncthreads();
    }

    lsum += __shfl_xor(lsum, 16);
    lsum += __shfl_xor(lsum, 32);
    float inv[4];
    #pragma unroll
    for (int r = 0; r < 4; ++r) inv[r] = 1.0f / __shfl(lsum, g * 4 + r);
    #pragma unroll
    for (int dt = 0; dt < 4; ++dt)
        #pragma unroll
        for (int r = 0; r < 4; ++r)
            attn[(size_t)(b * 1024 + q0 + g * 4 + r) * 1024 + h * 64 + dt * 16 + j] =
                (bf16)(o[dt][r] * inv[r]);
}

// ---------------------------------------------------------------------------
extern "C" void kernel_launch(void* const* d_in, const int* in_sizes, int n_in,
                              void* d_out, int out_size, void* d_ws, size_t ws_size,
                              hipStream_t stream)
{
    const float* x    = (const float*)d_in[0];
    const float* ln1g = (const float*)d_in[1];
    const float* ln1b = (const float*)d_in[2];
    const float* wq   = (const float*)d_in[3];
    const float* bq   = (const float*)d_in[4];
    const float* wk   = (const float*)d_in[5];
    const float* bk   = (const float*)d_in[6];
    const float* wv   = (const float*)d_in[7];
    const float* bv   = (const float*)d_in[8];
    const float* wo   = (const float*)d_in[9];
    const float* bo   = (const float*)d_in[10];
    const float* ln2g = (const float*)d_in[11];
    const float* ln2b = (const float*)d_in[12];
    const float* w1   = (const float*)d_in[13];
    const float* b1   = (const float*)d_in[14];
    const float* w2   = (const float*)d_in[15];
    const float* b2   = (const float*)d_in[16];

    char* ws = (char*)d_ws;
    bf16* wqkvT = (bf16*)ws;  ws += (size_t)3072 * 1024 * 2;
    bf16* woT   = (bf16*)ws;  ws += (size_t)1024 * 1024 * 2;
    bf16* w1T   = (bf16*)ws;  ws += (size_t)4096 * 1024 * 2;
    bf16* w2T   = (bf16*)ws;  ws += (size_t)1024 * 4096 * 2;
    float* bqkv = (float*)ws; ws += (size_t)3072 * 4;
    bf16* h     = (bf16*)ws;  ws += (size_t)8192 * 1024 * 2;
    bf16* qkv   = (bf16*)ws;  ws += (size_t)8192 * 3072 * 2;
    bf16* attn  = (bf16*)ws;  ws += (size_t)8192 * 1024 * 2;
    float* outf = (float*)ws; ws += (size_t)8192 * 1024 * 4;
    bf16* m1    = (bf16*)ws;  ws += (size_t)8192 * 4096 * 2;

    (void)hipFuncSetAttribute((const void*)gemm8p_kernel<0, 128>,
                              hipFuncAttributeMaxDynamicSharedMemorySize, 147456);
    (void)hipFuncSetAttribute((const void*)gemm8p_kernel<1, 128>,
                              hipFuncAttributeMaxDynamicSharedMemorySize, 147456);
    (void)hipFuncSetAttribute((const void*)gemm8p_kernel<2, 256>,
                              hipFuncAttributeMaxDynamicSharedMemorySize, 131072);
    (void)hipFuncSetAttribute((const void*)gemm8p_kernel<3, 128>,
                              hipFuncAttributeMaxDynamicSharedMemorySize, 147456);

    wtrans_kernel<<<dim3(16, 16), 256, 0, stream>>>(wq, wqkvT,                   1024, 1024);
    wtrans_kernel<<<dim3(16, 16), 256, 0, stream>>>(wk, wqkvT + 1024 * 1024,     1024, 1024);
    wtrans_kernel<<<dim3(16, 16), 256, 0, stream>>>(wv, wqkvT + 2 * 1024 * 1024, 1024, 1024);
    wtrans_kernel<<<dim3(16, 16), 256, 0, stream>>>(wo, woT, 1024, 1024);
    wtrans_kernel<<<dim3(64, 16), 256, 0, stream>>>(w1, w1T, 1024, 4096);
    wtrans_kernel<<<dim3(16, 64), 256, 0, stream>>>(w2, w2T, 4096, 1024);
    bias3_kernel<<<12, 256, 0, stream>>>(bq, bk, bv, bqkv);

    // LN1
    ln_kernel<<<8192, 256, 0, stream>>>(x, ln1g, ln1b, h);
    // QKV projection (BN=128, 768 blocks = 3 full rounds, depth-2 pipeline)
    gemm8p_kernel<0, 128><<<768, 512, 147456, stream>>>(h, wqkvT, bqkv, nullptr, qkv, 8192, 3072, 1024);
    // attention
    attn_kernel<<<dim3(16, 128), 256, 0, stream>>>(qkv, attn);
    // O projection + bias + residual(x) -> outf (BN=128, 256 blocks)
    gemm8p_kernel<1, 128><<<256, 512, 147456, stream>>>(attn, woT, bo, x, outf, 8192, 1024, 1024);
    // LN2
    ln_kernel<<<8192, 256, 0, stream>>>(outf, ln2g, ln2b, h);
    // MLP1 (verified 256x256 geometry, 512 blocks = 2 full rounds)
    gemm8p_kernel<2, 256><<<512, 512, 131072, stream>>>(h, w1T, b1, nullptr, m1, 8192, 4096, 1024);
    // MLP2 (BN=128, 256 blocks, K=4096)
    gemm8p_kernel<3, 128><<<256, 512, 147456, stream>>>(m1, w2T, b2, outf, (float*)d_out, 8192, 1024, 4096);
}

// Round 4
// 553.167 us; speedup vs baseline: 1.0839x; 1.0117x over previous
//
#include <hip/hip_runtime.h>
#include <cstdint>

typedef __bf16 bf16;
typedef __attribute__((ext_vector_type(8))) __bf16 bf16x8;
typedef __attribute__((ext_vector_type(4))) __bf16 bf16x4;
typedef __attribute__((ext_vector_type(4))) float f32x4;
typedef __attribute__((ext_vector_type(8))) unsigned short u16x8;

#define AS1C(p) ((const __attribute__((address_space(1))) void*)(p))
#define AS3(p)  ((__attribute__((address_space(3))) void*)(p))

__device__ __forceinline__ float gelu_exact(float v) {
    return 0.5f * v * (1.0f + erff(v * 0.7071067811865476f));
}

// ---------------------------------------------------------------------------
// Weight transpose + fp32->bf16 convert: w [K][N] fp32 -> wt [N][K] bf16
// ---------------------------------------------------------------------------
__global__ __launch_bounds__(256, 1) void wtrans_kernel(
    const float* __restrict__ w, bf16* __restrict__ wt, int K, int N)
{
    __shared__ float tile[64][65];
    const int k0 = blockIdx.y * 64, n0 = blockIdx.x * 64;
    const int tid = threadIdx.x;
    {
        const int kl = tid >> 2, nc = (tid & 3) * 16;
        #pragma unroll
        for (int i = 0; i < 4; ++i) {
            const float4 v = *(const float4*)&w[(size_t)(k0 + kl) * N + n0 + nc + i * 4];
            tile[kl][nc + i * 4 + 0] = v.x;
            tile[kl][nc + i * 4 + 1] = v.y;
            tile[kl][nc + i * 4 + 2] = v.z;
            tile[kl][nc + i * 4 + 3] = v.w;
        }
    }
    __syncthreads();
    {
        const int nl = tid >> 2, kc = (tid & 3) * 16;
        #pragma unroll
        for (int i = 0; i < 4; ++i) {
            bf16x4 o4;
            o4[0] = (bf16)tile[kc + i * 4 + 0][nl];
            o4[1] = (bf16)tile[kc + i * 4 + 1][nl];
            o4[2] = (bf16)tile[kc + i * 4 + 2][nl];
            o4[3] = (bf16)tile[kc + i * 4 + 3][nl];
            *(bf16x4*)&wt[(size_t)(n0 + nl) * K + k0 + kc + i * 4] = o4;
        }
    }
}

__global__ void bias3_kernel(const float* __restrict__ a, const float* __restrict__ b,
                             const float* __restrict__ c, float* __restrict__ o)
{
    const int i = blockIdx.x * 256 + threadIdx.x;
    o[i] = (i < 1024) ? a[i] : (i < 2048 ? b[i - 1024] : c[i - 2048]);
}

// ---------------------------------------------------------------------------
// LayerNorm over rows of 1024 fp32 -> bf16. grid 8192 x 256
// ---------------------------------------------------------------------------
__global__ __launch_bounds__(256, 1) void ln_kernel(
    const float* __restrict__ x, const float* __restrict__ gw,
    const float* __restrict__ bw, bf16* __restrict__ out)
{
    const int row = blockIdx.x, tid = threadIdx.x;
    const float4 v = *(const float4*)&x[(size_t)row * 1024 + tid * 4];
    float s = v.x + v.y + v.z + v.w;
    float q = v.x * v.x + v.y * v.y + v.z * v.z + v.w * v.w;
    #pragma unroll
    for (int off = 32; off > 0; off >>= 1) {
        s += __shfl_xor(s, off);
        q += __shfl_xor(q, off);
    }
    __shared__ float red[8];
    if ((tid & 63) == 0) { red[tid >> 6] = s; red[4 + (tid >> 6)] = q; }
    __syncthreads();
    s = red[0] + red[1] + red[2] + red[3];
    q = red[4] + red[5] + red[6] + red[7];
    const float mu = s * (1.f / 1024.f);
    const float rs = rsqrtf(q * (1.f / 1024.f) - mu * mu + 1e-5f);
    const float4 gg = *(const float4*)&gw[tid * 4];
    const float4 bb = *(const float4*)&bw[tid * 4];
    bf16x4 o4;
    o4[0] = (bf16)((v.x - mu) * rs * gg.x + bb.x);
    o4[1] = (bf16)((v.y - mu) * rs * gg.y + bb.y);
    o4[2] = (bf16)((v.z - mu) * rs * gg.z + bb.z);
    o4[3] = (bf16)((v.w - mu) * rs * gg.w + bb.w);
    *(bf16x4*)&out[(size_t)row * 1024 + tid * 4] = o4;
}

// ---------------------------------------------------------------------------
// 8-phase 256xBN GEMM. C = A @ BT^T + bias, fused epilogue.
// 512 threads = 8 waves, BK=64 (128B rows). LDS swizzle: toggle byte bits
// 4-6 by bits 8-10 (row bits 1-3) -> 2-way conflicts (free). Applied as
// linear global_load_lds dest + pre-permuted global source + swizzled
// ds_read (rule: both-sides-or-neither).
// BN=256: 2 buffers, depth-1, vmcnt(0)/tile; 4 phases x 16 MFMA.
// BN=128: 3 buffers, depth-2, vmcnt(6) counted; 2 phases x 16 MFMA.
// ---------------------------------------------------------------------------
template<int BCH>
__device__ __forceinline__ void stage_tile(
    const bf16* __restrict__ A, const bf16* __restrict__ BT, int K,
    int bm, int bn, int k0, char* buf, int wid, int rsub, int ksub)
{
    #pragma unroll
    for (int c = 0; c < 4; ++c) {
        const bf16* src = A + (size_t)(bm + c * 64 + wid * 8 + rsub) * K + k0 + ksub;
        __builtin_amdgcn_global_load_lds(AS1C(src), AS3(buf + (c * 8 + wid) * 1024), 16, 0, 0);
    }
    #pragma unroll
    for (int c = 0; c < BCH; ++c) {
        const bf16* src = BT + (size_t)(bn + c * 64 + wid * 8 + rsub) * K + k0 + ksub;
        __builtin_amdgcn_global_load_lds(AS1C(src), AS3(buf + 32768 + (c * 8 + wid) * 1024), 16, 0, 0);
    }
}

template<int EPI, int BN>
__global__ __launch_bounds__(512, 2) void gemm8p_kernel(
    const bf16* __restrict__ A, const bf16* __restrict__ BT,
    const float* __restrict__ bias, const float* __restrict__ res,
    void* __restrict__ out, int M, int N, int K)
{
    constexpr int PWM = (BN == 256) ? 128 : 64;
    constexpr int PWN = 64;
    constexpr int MF = PWM / 16;
    constexpr int NF = 4;
    constexpr int PH_M = (BN == 256) ? 4 : 2;    // A frags per phase
    constexpr int PH_N = (BN == 256) ? 2 : 4;    // B frags per phase
    constexpr int QN = NF / PH_N;                // 2 or 1
    constexpr int NPH = (MF / PH_M) * QN;        // 4 or 2 phases per tile
    constexpr int BCH = BN / 64;
    constexpr int BUFB = (256 + BN) * 128;
    constexpr int NBUF = (BN == 256) ? 2 : 3;
    extern __shared__ char lds[];

    const int tid = threadIdx.x;
    const int lane = tid & 63, wid = tid >> 6;
    const int wr = (BN == 256) ? (wid >> 2) : (wid >> 1);
    const int wc = (BN == 256) ? (wid & 3) : (wid & 1);
    const int j = lane & 15, g = lane >> 4;
    // source pre-permute matching the 3-bit read swizzle
    const int lanep = (lane & 7) ^ ((lane >> 4) & 3) ^ ((wid & 1) << 2);
    const int rsub = lane >> 3, ksub = lanep * 8;

    const int nbn = N / BN;
    const int nwg = (M / 256) * nbn;
    const int bid = blockIdx.x;
    const int wg = (bid & 7) * (nwg >> 3) + (bid >> 3);
    const int bm = (wg / nbn) * 256;
    const int bn = (wg % nbn) * BN;

    f32x4 acc[MF][NF] = {};
    const int NT = K >> 6;

    stage_tile<BCH>(A, BT, K, bm, bn, 0, lds, wid, rsub, ksub);
    if constexpr (NBUF == 3) {
        stage_tile<BCH>(A, BT, K, bm, bn, 64, lds + BUFB, wid, rsub, ksub);
        asm volatile("s_waitcnt vmcnt(6)" ::: "memory");
    } else {
        asm volatile("s_waitcnt vmcnt(0)" ::: "memory");
    }
    __builtin_amdgcn_s_barrier();

    for (int t = 0; t < NT; ++t) {
        char* buf = lds + ((NBUF == 2) ? (t & 1) : (t % 3)) * BUFB;
        #pragma unroll
        for (int ph = 0; ph < NPH; ++ph) {
            const int qm = ph / QN, qn = ph % QN;
            bf16x8 af[PH_M][2], bfr[PH_N][2];
            #pragma unroll
            for (int mf = 0; mf < PH_M; ++mf)
                #pragma unroll
                for (int ks = 0; ks < 2; ++ks) {
                    const int R = wr * PWM + (qm * PH_M + mf) * 16 + j;
                    uint32_t lb = (uint32_t)(R * 128 + ks * 64 + g * 16);
                    lb ^= (lb >> 4) & 0x70u;
                    af[mf][ks] = *(const bf16x8*)(buf + lb);
                }
            #pragma unroll
            for (int nf = 0; nf < PH_N; ++nf)
                #pragma unroll
                for (int ks = 0; ks < 2; ++ks) {
                    const int R = wc * PWN + (qn * PH_N + nf) * 16 + j;
                    uint32_t lb = (uint32_t)(R * 128 + ks * 64 + g * 16);
                    lb ^= (lb >> 4) & 0x70u;
                    bfr[nf][ks] = *(const bf16x8*)(buf + 32768 + lb);
                }
            if (ph == 0) {
                if constexpr (NBUF == 2) {
                    if (t + 1 < NT)
                        stage_tile<BCH>(A, BT, K, bm, bn, (t + 1) << 6,
                                        lds + ((t + 1) & 1) * BUFB, wid, rsub, ksub);
                } else {
                    if (t + 2 < NT)
                        stage_tile<BCH>(A, BT, K, bm, bn, (t + 2) << 6,
                                        lds + ((t + 2) % 3) * BUFB, wid, rsub, ksub);
                }
            }
            __builtin_amdgcn_s_barrier();
            asm volatile("s_waitcnt lgkmcnt(0)" ::: "memory");
            __builtin_amdgcn_sched_barrier(0);
            __builtin_amdgcn_s_setprio(1);
            #pragma unroll
            for (int mf = 0; mf < PH_M; ++mf)
                #pragma unroll
                for (int nf = 0; nf < PH_N; ++nf)
                    #pragma unroll
                    for (int ks = 0; ks < 2; ++ks)
                        acc[qm * PH_M + mf][qn * PH_N + nf] =
                            __builtin_amdgcn_mfma_f32_16x16x32_bf16(
                                af[mf][ks], bfr[nf][ks],
                                acc[qm * PH_M + mf][qn * PH_N + nf], 0, 0, 0);
            __builtin_amdgcn_s_setprio(0);
            if (ph == NPH - 1) {
                if constexpr (NBUF == 2) {
                    asm volatile("s_waitcnt vmcnt(0)" ::: "memory");
                } else {
                    if (t + 2 < NT) asm volatile("s_waitcnt vmcnt(6)" ::: "memory");
                    else            asm volatile("s_waitcnt vmcnt(0)" ::: "memory");
                }
            }
            __builtin_amdgcn_s_barrier();
        }
    }

    const int row0 = bm + wr * PWM;
    const int col0 = bn + wc * PWN;
    #pragma unroll
    for (int nf = 0; nf < NF; ++nf) {
        const int col = col0 + nf * 16 + j;
        const float bs = bias[col];
        #pragma unroll
        for (int mf = 0; mf < MF; ++mf) {
            #pragma unroll
            for (int r = 0; r < 4; ++r) {
                const int row = row0 + mf * 16 + g * 4 + r;
                float v = acc[mf][nf][r] + bs;
                if constexpr (EPI == 2 || EPI == 3) v = gelu_exact(v);
                if constexpr (EPI == 1 || EPI == 3) {
                    v += res[(size_t)row * N + col];
                    ((float*)out)[(size_t)row * N + col] = v;
                } else {
                    ((bf16*)out)[(size_t)row * N + col] = (bf16)v;
                }
            }
        }
    }
}

// ---------------------------------------------------------------------------
// Flash attention v3: swapped QK^T (P born in PV A-fragment layout) +
// K-fragment register double-buffer prefetch (hides L2 latency under
// softmax+PV). V^T double-buffered in LDS (u32-packed, conflict-free).
// ---------------------------------------------------------------------------
__device__ __forceinline__ void attn_iter(
    int c, const bf16* __restrict__ Kp, const bf16* __restrict__ Vp,
    uint32_t (&vTu)[2][64][36],
    bf16x8 (&kf)[4][2], bf16x8 (&kfn)[4][2],
    const bf16x8& qf0, const bf16x8& qf1,
    f32x4 (&o)[4], float& mrun, float& lsum,
    int kp, int d0, int jperm, int g, int j)
{
    const f32x4 zero = {0.f, 0.f, 0.f, 0.f};
    const bool pf = (c + 1 < 16);

    // V prefetch for c+1 (global -> regs, consumed after softmax)
    u16x8 r0, r1;
    if (pf) {
        const size_t vb = (size_t)((c + 1) * 64 + kp) * 3072 + d0;
        r0 = *(const u16x8*)&Vp[vb];
        r1 = *(const u16x8*)&Vp[vb + 3072];
    }

    // QK^T from prefetched K fragments
    f32x4 s[4];
    #pragma unroll
    for (int t = 0; t < 4; ++t) {
        s[t] = __builtin_amdgcn_mfma_f32_16x16x32_bf16(kf[t][0], qf0, zero, 0, 0, 0);
        s[t] = __builtin_amdgcn_mfma_f32_16x16x32_bf16(kf[t][1], qf1, s[t], 0, 0, 0);
    }

    // K prefetch for c+1 (hidden under softmax + PV)
    if (pf) {
        #pragma unroll
        for (int t = 0; t < 4; ++t) {
            const int key = (c + 1) * 64 + (t >> 1) * 32 + jperm + (t & 1) * 4;
            kfn[t][0] = *(const bf16x8*)&Kp[(size_t)key * 3072 + g * 8];
            kfn[t][1] = *(const bf16x8*)&Kp[(size_t)key * 3072 + 32 + g * 8];
        }
    }

    // online softmax (row = q entirely in-lane, +2 shfl)
    float cur = fmaxf(fmaxf(s[0][0], s[0][1]), fmaxf(s[0][2], s[0][3]));
    #pragma unroll
    for (int t = 1; t < 4; ++t)
        cur = fmaxf(cur, fmaxf(fmaxf(s[t][0], s[t][1]), fmaxf(s[t][2], s[t][3])));
    cur = fmaxf(cur, __shfl_xor(cur, 16));
    cur = fmaxf(cur, __shfl_xor(cur, 32));

    if (!__all(cur - mrun <= 8.0f)) {        // defer-max (THR=8)
        const float mnew = fmaxf(mrun, cur);
        const float alpha = __expf(mrun - mnew);
        float al[4];
        #pragma unroll
        for (int r = 0; r < 4; ++r) al[r] = __shfl(alpha, g * 4 + r);
        #pragma unroll
        for (int dt = 0; dt < 4; ++dt)
            #pragma unroll
            for (int r = 0; r < 4; ++r) o[dt][r] *= al[r];
        lsum *= alpha;
        mrun = mnew;
    }
    float ps = 0.f;
    #pragma unroll
    for (int t = 0; t < 4; ++t)
        #pragma unroll
        for (int r = 0; r < 4; ++r) {
            const float p = __expf(s[t][r] - mrun);
            s[t][r] = p;
            ps += p;
        }
    lsum += ps;

    bf16x8 pa0, pa1;
    #pragma unroll
    for (int r = 0; r < 4; ++r) {
        pa0[r]     = (bf16)s[0][r];
        pa0[4 + r] = (bf16)s[1][r];
        pa1[r]     = (bf16)s[2][r];
        pa1[4 + r] = (bf16)s[3][r];
    }

    // write V block c+1 into the other LDS buffer
    if (pf) {
        #pragma unroll
        for (int i = 0; i < 8; ++i)
            vTu[(c + 1) & 1][d0 + i][kp >> 1] = (uint32_t)r0[i] | ((uint32_t)r1[i] << 16);
    }

    // O += P V
    #pragma unroll
    for (int dt = 0; dt < 4; ++dt) {
        const bf16* vrow = (const bf16*)&vTu[c & 1][dt * 16 + j][0];
        const bf16x8 vb0 = *(const bf16x8*)(vrow + g * 8);
        const bf16x8 vb1 = *(const bf16x8*)(vrow + 32 + g * 8);
        o[dt] = __builtin_amdgcn_mfma_f32_16x16x32_bf16(pa0, vb0, o[dt], 0, 0, 0);
        o[dt] = __builtin_amdgcn_mfma_f32_16x16x32_bf16(pa1, vb1, o[dt], 0, 0, 0);
    }
    __syncthreads();
}

__global__ __launch_bounds__(256, 1) void attn_kernel(
    const bf16* __restrict__ qkv, bf16* __restrict__ attn)
{
    const int tid = threadIdx.x;
    const int lane = tid & 63, wid = tid >> 6;
    const int j = lane & 15, g = lane >> 4;

    const int lin = blockIdx.x + blockIdx.y * 16;
    const int virt = (lin & 7) * 256 + (lin >> 3);
    const int bh = virt >> 4, qt = virt & 15;
    const int b = bh >> 4, h = bh & 15;
    const int q0 = qt * 64 + wid * 16;

    const bf16* Qp = qkv + (size_t)b * 1024 * 3072 + h * 64;
    const bf16* Kp = Qp + 1024;
    const bf16* Vp = Qp + 2048;

    __shared__ __attribute__((aligned(16))) uint32_t vTu[2][64][36];

    const int kp = (tid & 31) * 2;
    const int d0 = (tid >> 5) * 8;
    {
        const u16x8 r0 = *(const u16x8*)&Vp[(size_t)kp * 3072 + d0];
        const u16x8 r1 = *(const u16x8*)&Vp[(size_t)(kp + 1) * 3072 + d0];
        #pragma unroll
        for (int i = 0; i < 8; ++i)
            vTu[0][d0 + i][kp >> 1] = (uint32_t)r0[i] | ((uint32_t)r1[i] << 16);
    }

    bf16x8 qf0 = *(const bf16x8*)&Qp[(size_t)(q0 + j) * 3072 + g * 8];
    bf16x8 qf1 = *(const bf16x8*)&Qp[(size_t)(q0 + j) * 3072 + 32 + g * 8];
    #pragma unroll
    for (int e = 0; e < 8; ++e) {
        qf0[e] = (bf16)((float)qf0[e] * 0.03125f);
        qf1[e] = (bf16)((float)qf1[e] * 0.03125f);
    }

    const int jperm = (j >> 2) * 8 + (j & 3);

    f32x4 o[4] = {};
    float mrun = -1e30f, lsum = 0.f;

    // preload K fragments for block 0
    bf16x8 kfA[4][2], kfB[4][2];
    #pragma unroll
    for (int t = 0; t < 4; ++t) {
        const int key = (t >> 1) * 32 + jperm + (t & 1) * 4;
        kfA[t][0] = *(const bf16x8*)&Kp[(size_t)key * 3072 + g * 8];
        kfA[t][1] = *(const bf16x8*)&Kp[(size_t)key * 3072 + 32 + g * 8];
    }

    __syncthreads();

    for (int cc = 0; cc < 16; cc += 2) {
        attn_iter(cc,     Kp, Vp, vTu, kfA, kfB, qf0, qf1, o, mrun, lsum, kp, d0, jperm, g, j);
        attn_iter(cc + 1, Kp, Vp, vTu, kfB, kfA, qf0, qf1, o, mrun, lsum, kp, d0, jperm, g, j);
    }

    lsum += __shfl_xor(lsum, 16);
    lsum += __shfl_xor(lsum, 32);
    float inv[4];
    #pragma unroll
    for (int r = 0; r < 4; ++r) inv[r] = 1.0f / __shfl(lsum, g * 4 + r);
    #pragma unroll
    for (int dt = 0; dt < 4; ++dt)
        #pragma unroll
        for (int r = 0; r < 4; ++r)
            attn[(size_t)(b * 1024 + q0 + g * 4 + r) * 1024 + h * 64 + dt * 16 + j] =
                (bf16)(o[dt][r] * inv[r]);
}

// ---------------------------------------------------------------------------
extern "C" void kernel_launch(void* const* d_in, const int* in_sizes, int n_in,
                              void* d_out, int out_size, void* d_ws, size_t ws_size,
                              hipStream_t stream)
{
    const float* x    = (const float*)d_in[0];
    const float* ln1g = (const float*)d_in[1];
    const float* ln1b = (const float*)d_in[2];
    const float* wq   = (const float*)d_in[3];
    const float* bq   = (const float*)d_in[4];
    const float* wk   = (const float*)d_in[5];
    const float* bk   = (const float*)d_in[6];
    const float* wv   = (const float*)d_in[7];
    const float* bv   = (const float*)d_in[8];
    const float* wo   = (const float*)d_in[9];
    const float* bo   = (const float*)d_in[10];
    const float* ln2g = (const float*)d_in[11];
    const float* ln2b = (const float*)d_in[12];
    const float* w1   = (const float*)d_in[13];
    const float* b1   = (const float*)d_in[14];
    const float* w2   = (const float*)d_in[15];
    const float* b2   = (const float*)d_in[16];

    char* ws = (char*)d_ws;
    bf16* wqkvT = (bf16*)ws;  ws += (size_t)3072 * 1024 * 2;
    bf16* woT   = (bf16*)ws;  ws += (size_t)1024 * 1024 * 2;
    bf16* w1T   = (bf16*)ws;  ws += (size_t)4096 * 1024 * 2;
    bf16* w2T   = (bf16*)ws;  ws += (size_t)1024 * 4096 * 2;
    float* bqkv = (float*)ws; ws += (size_t)3072 * 4;
    bf16* h     = (bf16*)ws;  ws += (size_t)8192 * 1024 * 2;
    bf16* qkv   = (bf16*)ws;  ws += (size_t)8192 * 3072 * 2;
    bf16* attn  = (bf16*)ws;  ws += (size_t)8192 * 1024 * 2;
    float* outf = (float*)ws; ws += (size_t)8192 * 1024 * 4;
    bf16* m1    = (bf16*)ws;  ws += (size_t)8192 * 4096 * 2;

    (void)hipFuncSetAttribute((const void*)gemm8p_kernel<0, 128>,
                              hipFuncAttributeMaxDynamicSharedMemorySize, 147456);
    (void)hipFuncSetAttribute((const void*)gemm8p_kernel<1, 128>,
                              hipFuncAttributeMaxDynamicSharedMemorySize, 147456);
    (void)hipFuncSetAttribute((const void*)gemm8p_kernel<2, 256>,
                              hipFuncAttributeMaxDynamicSharedMemorySize, 131072);
    (void)hipFuncSetAttribute((const void*)gemm8p_kernel<3, 128>,
                              hipFuncAttributeMaxDynamicSharedMemorySize, 147456);

    wtrans_kernel<<<dim3(16, 16), 256, 0, stream>>>(wq, wqkvT,                   1024, 1024);
    wtrans_kernel<<<dim3(16, 16), 256, 0, stream>>>(wk, wqkvT + 1024 * 1024,     1024, 1024);
    wtrans_kernel<<<dim3(16, 16), 256, 0, stream>>>(wv, wqkvT + 2 * 1024 * 1024, 1024, 1024);
    wtrans_kernel<<<dim3(16, 16), 256, 0, stream>>>(wo, woT, 1024, 1024);
    wtrans_kernel<<<dim3(64, 16), 256, 0, stream>>>(w1, w1T, 1024, 4096);
    wtrans_kernel<<<dim3(16, 64), 256, 0, stream>>>(w2, w2T, 4096, 1024);
    bias3_kernel<<<12, 256, 0, stream>>>(bq, bk, bv, bqkv);

    // LN1
    ln_kernel<<<8192, 256, 0, stream>>>(x, ln1g, ln1b, h);
    // QKV projection (BN=128, 768 blocks, depth-2 pipeline)
    gemm8p_kernel<0, 128><<<768, 512, 147456, stream>>>(h, wqkvT, bqkv, nullptr, qkv, 8192, 3072, 1024);
    // attention
    attn_kernel<<<dim3(16, 128), 256, 0, stream>>>(qkv, attn);
    // O projection + bias + residual(x) -> outf
    gemm8p_kernel<1, 128><<<256, 512, 147456, stream>>>(attn, woT, bo, x, outf, 8192, 1024, 1024);
    // LN2
    ln_kernel<<<8192, 256, 0, stream>>>(outf, ln2g, ln2b, h);
    // MLP1 (256x256)
    gemm8p_kernel<2, 256><<<512, 512, 131072, stream>>>(h, w1T, b1, nullptr, m1, 8192, 4096, 1024);
    // MLP2 (BN=128, K=4096)
    gemm8p_kernel<3, 128><<<256, 512, 147456, stream>>>(m1, w2T, b2, outf, (float*)d_out, 8192, 1024, 4096);
}

// Round 5
// 540.285 us; speedup vs baseline: 1.1098x; 1.0238x over previous
//
#include <hip/hip_runtime.h>
#include <cstdint>

typedef __bf16 bf16;
typedef __attribute__((ext_vector_type(8))) __bf16 bf16x8;
typedef __attribute__((ext_vector_type(4))) __bf16 bf16x4;
typedef __attribute__((ext_vector_type(4))) float f32x4;
typedef __attribute__((ext_vector_type(8))) unsigned short u16x8;

#define AS1C(p) ((const __attribute__((address_space(1))) void*)(p))
#define AS3(p)  ((__attribute__((address_space(3))) void*)(p))

__device__ __forceinline__ float gelu_exact(float v) {
    return 0.5f * v * (1.0f + erff(v * 0.7071067811865476f));
}

// ---------------------------------------------------------------------------
// Weight transpose + fp32->bf16 convert: w [K][N] fp32 -> wt [N][K] bf16
// ---------------------------------------------------------------------------
__global__ __launch_bounds__(256, 1) void wtrans_kernel(
    const float* __restrict__ w, bf16* __restrict__ wt, int K, int N)
{
    __shared__ float tile[64][65];
    const int k0 = blockIdx.y * 64, n0 = blockIdx.x * 64;
    const int tid = threadIdx.x;
    {
        const int kl = tid >> 2, nc = (tid & 3) * 16;
        #pragma unroll
        for (int i = 0; i < 4; ++i) {
            const float4 v = *(const float4*)&w[(size_t)(k0 + kl) * N + n0 + nc + i * 4];
            tile[kl][nc + i * 4 + 0] = v.x;
            tile[kl][nc + i * 4 + 1] = v.y;
            tile[kl][nc + i * 4 + 2] = v.z;
            tile[kl][nc + i * 4 + 3] = v.w;
        }
    }
    __syncthreads();
    {
        const int nl = tid >> 2, kc = (tid & 3) * 16;
        #pragma unroll
        for (int i = 0; i < 4; ++i) {
            bf16x4 o4;
            o4[0] = (bf16)tile[kc + i * 4 + 0][nl];
            o4[1] = (bf16)tile[kc + i * 4 + 1][nl];
            o4[2] = (bf16)tile[kc + i * 4 + 2][nl];
            o4[3] = (bf16)tile[kc + i * 4 + 3][nl];
            *(bf16x4*)&wt[(size_t)(n0 + nl) * K + k0 + kc + i * 4] = o4;
        }
    }
}

__global__ void bias3_kernel(const float* __restrict__ a, const float* __restrict__ b,
                             const float* __restrict__ c, float* __restrict__ o)
{
    const int i = blockIdx.x * 256 + threadIdx.x;
    o[i] = (i < 1024) ? a[i] : (i < 2048 ? b[i - 1024] : c[i - 2048]);
}

// ---------------------------------------------------------------------------
// LayerNorm over rows of 1024 fp32 -> bf16. grid 8192 x 256
// ---------------------------------------------------------------------------
__global__ __launch_bounds__(256, 1) void ln_kernel(
    const float* __restrict__ x, const float* __restrict__ gw,
    const float* __restrict__ bw, bf16* __restrict__ out)
{
    const int row = blockIdx.x, tid = threadIdx.x;
    const float4 v = *(const float4*)&x[(size_t)row * 1024 + tid * 4];
    float s = v.x + v.y + v.z + v.w;
    float q = v.x * v.x + v.y * v.y + v.z * v.z + v.w * v.w;
    #pragma unroll
    for (int off = 32; off > 0; off >>= 1) {
        s += __shfl_xor(s, off);
        q += __shfl_xor(q, off);
    }
    __shared__ float red[8];
    if ((tid & 63) == 0) { red[tid >> 6] = s; red[4 + (tid >> 6)] = q; }
    __syncthreads();
    s = red[0] + red[1] + red[2] + red[3];
    q = red[4] + red[5] + red[6] + red[7];
    const float mu = s * (1.f / 1024.f);
    const float rs = rsqrtf(q * (1.f / 1024.f) - mu * mu + 1e-5f);
    const float4 gg = *(const float4*)&gw[tid * 4];
    const float4 bb = *(const float4*)&bw[tid * 4];
    bf16x4 o4;
    o4[0] = (bf16)((v.x - mu) * rs * gg.x + bb.x);
    o4[1] = (bf16)((v.y - mu) * rs * gg.y + bb.y);
    o4[2] = (bf16)((v.z - mu) * rs * gg.z + bb.z);
    o4[3] = (bf16)((v.w - mu) * rs * gg.w + bb.w);
    *(bf16x4*)&out[(size_t)row * 1024 + tid * 4] = o4;
}

// ---------------------------------------------------------------------------
// m201-geometry GEMM: per-wave output 128x64 (MF=8, NF=4), BK=64, BN=256.
// WM=2: BM=256, 512 thr (8 waves 2Mx4N).  WM=1: BM=128, 256 thr (4 waves 1x4).
// Wave wc owns cols {wc*32..+31} U {128+wc*32..+31} so phase qn consumes
// B rows [qn*128, qn*128+128) = whole stage groups.
// 4 phases/K-tile (qm,qn quadrants), 16 MFMA each. Staging in consumption
// order, uniform counted vmcnt (never 0 mid-loop). 3-bit LDS XOR swizzle
// (byte bits 4-6 ^= row bits 1-3) via pre-permuted global source (linear
// global_load_lds dest) + swizzled ds_read.
// ---------------------------------------------------------------------------
constexpr int GORD2[8]  = {0, 2, 16, 17, 18, 19, 1, 3};             // A0 A2 B0 B1 | B2 B3 | A1 A3
constexpr int GOFF2[5]  = {0, 4, 6, 8, 8};
constexpr int GORD1[12] = {0, 1, 16, 17, 18, 19, 20, 21, 22, 23, 2, 3}; // A0 A1 B0-B3 | B4-B7 | A2 A3
constexpr int GOFF1[5]  = {0, 6, 10, 12, 12};

template<int EPI, int WM>
__global__ __launch_bounds__(WM * 256, 2) void gemm_m201_kernel(
    const bf16* __restrict__ A, const bf16* __restrict__ BT,
    const float* __restrict__ bias, const float* __restrict__ res,
    void* __restrict__ out, int M, int N, int K)
{
    constexpr int BM = WM * 128;
    constexpr int THREADS = WM * 256;
    constexpr int RPG = THREADS / 8;         // rows per stage group (64 / 32)
    constexpr int ABYTES = BM * 128;
    constexpr int BUFB = ABYTES + 256 * 128;
    constexpr int NSG = (WM == 2) ? 8 : 12;
    extern __shared__ char lds[];

    const int tid = threadIdx.x;
    const int lane = tid & 63, wid = tid >> 6;
    const int wr = (WM == 2) ? (wid >> 2) : 0;
    const int wc = wid & 3;
    const int j = lane & 15, g = lane >> 4;
    // global-source k-permutation matching the 3-bit read swizzle
    const int lanep = (lane & 7) ^ ((lane >> 4) & 3) ^ ((wid & 1) << 2);
    const int ksub = lanep * 8;

    const int nbn = N >> 8;
    const int nwg = (M / BM) * nbn;
    const int bid = blockIdx.x;
    const int wg = (bid & 7) * (nwg >> 3) + (bid >> 3);
    const int bm = (wg / nbn) * BM;
    const int bn = (wg % nbn) << 8;

    auto stage_one = [&](int id, int k0, char* obuf) {
        const int isB = id >> 4, gg = id & 15;
        const bf16* base = isB ? BT : A;
        const int rowbase = (isB ? bn : bm) + gg * RPG;
        const bf16* src = base + (size_t)(rowbase + (tid >> 3)) * K + k0 + ksub;
        char* dst = obuf + (isB ? ABYTES : 0) + gg * (RPG * 128) + wid * 1024;
        __builtin_amdgcn_global_load_lds(AS1C(src), AS3(dst), 16, 0, 0);
    };

    f32x4 acc[8][4] = {};
    const int NT = K >> 6;

    // prologue: stage tile 0 in schedule order, wait for phase-0 groups
    #pragma unroll
    for (int i = 0; i < NSG; ++i)
        stage_one((WM == 2) ? GORD2[i] : GORD1[i], 0, lds);
    if constexpr (WM == 2) asm volatile("s_waitcnt vmcnt(4)" ::: "memory");
    else                   asm volatile("s_waitcnt vmcnt(6)" ::: "memory");
    __builtin_amdgcn_s_barrier();

    for (int t = 0; t < NT; ++t) {
        char* buf  = lds + (t & 1) * BUFB;
        char* obuf = lds + ((t + 1) & 1) * BUFB;
        #pragma unroll
        for (int ph = 0; ph < 4; ++ph) {
            const int qm = ph >> 1, qn = ph & 1;
            bf16x8 af[4][2], bfr[2][2];
            #pragma unroll
            for (int mf = 0; mf < 4; ++mf)
                #pragma unroll
                for (int ks = 0; ks < 2; ++ks) {
                    const int R = wr * 128 + (qm * 4 + mf) * 16 + j;
                    uint32_t lb = (uint32_t)(R * 128 + ks * 64 + g * 16);
                    lb ^= (lb >> 4) & 0x70u;
                    af[mf][ks] = *(const bf16x8*)(buf + lb);
                }
            #pragma unroll
            for (int nfi = 0; nfi < 2; ++nfi)
                #pragma unroll
                for (int ks = 0; ks < 2; ++ks) {
                    const int R = qn * 128 + wc * 32 + nfi * 16 + j;
                    uint32_t lb = (uint32_t)(R * 128 + ks * 64 + g * 16);
                    lb ^= (lb >> 4) & 0x70u;
                    bfr[nfi][ks] = *(const bf16x8*)(buf + ABYTES + lb);
                }
            if (t + 1 < NT) {
                if constexpr (WM == 2) {
                    #pragma unroll
                    for (int i = 0; i < 8; ++i)
                        if (i >= GOFF2[ph] && i < GOFF2[ph + 1])
                            stage_one(GORD2[i], (t + 1) << 6, obuf);
                } else {
                    #pragma unroll
                    for (int i = 0; i < 12; ++i)
                        if (i >= GOFF1[ph] && i < GOFF1[ph + 1])
                            stage_one(GORD1[i], (t + 1) << 6, obuf);
                }
            }
            __builtin_amdgcn_s_barrier();
            asm volatile("s_waitcnt lgkmcnt(0)" ::: "memory");
            __builtin_amdgcn_sched_barrier(0);
            __builtin_amdgcn_s_setprio(1);
            #pragma unroll
            for (int mf = 0; mf < 4; ++mf)
                #pragma unroll
                for (int nfi = 0; nfi < 2; ++nfi)
                    #pragma unroll
                    for (int ks = 0; ks < 2; ++ks)
                        acc[qm * 4 + mf][qn * 2 + nfi] =
                            __builtin_amdgcn_mfma_f32_16x16x32_bf16(
                                af[mf][ks], bfr[nfi][ks],
                                acc[qm * 4 + mf][qn * 2 + nfi], 0, 0, 0);
            __builtin_amdgcn_s_setprio(0);
            // counted end-of-phase waits (derived; never 0 mid-loop)
            if constexpr (WM == 2) {
                if (ph == 0 || ph == 1) asm volatile("s_waitcnt vmcnt(6)" ::: "memory");
                else if (ph == 2)       asm volatile("s_waitcnt vmcnt(8)" ::: "memory");
                else                    asm volatile("s_waitcnt vmcnt(4)" ::: "memory");
            } else {
                if (ph == 0)            asm volatile("s_waitcnt vmcnt(8)" ::: "memory");
                else if (ph == 1)       asm volatile("s_waitcnt vmcnt(10)" ::: "memory");
                else if (ph == 2)       asm volatile("s_waitcnt vmcnt(12)" ::: "memory");
                else                    asm volatile("s_waitcnt vmcnt(6)" ::: "memory");
            }
            __builtin_amdgcn_s_barrier();
        }
    }

    const int row0 = bm + wr * 128;
    #pragma unroll
    for (int nf = 0; nf < 4; ++nf) {
        const int col = bn + (nf >> 1) * 128 + wc * 32 + (nf & 1) * 16 + j;
        const float bs = bias[col];
        #pragma unroll
        for (int mf = 0; mf < 8; ++mf) {
            #pragma unroll
            for (int r = 0; r < 4; ++r) {
                const int row = row0 + mf * 16 + g * 4 + r;
                float v = acc[mf][nf][r] + bs;
                if constexpr (EPI == 2 || EPI == 3) v = gelu_exact(v);
                if constexpr (EPI == 1 || EPI == 3) {
                    v += res[(size_t)row * N + col];
                    ((float*)out)[(size_t)row * N + col] = v;
                } else {
                    ((bf16*)out)[(size_t)row * N + col] = (bf16)v;
                }
            }
        }
    }
}

// ---------------------------------------------------------------------------
// Flash attention (r4 structure, split into 2 dispatches via bh_base for
// rocprof visibility of GEMM dispatches).
// ---------------------------------------------------------------------------
__device__ __forceinline__ void attn_iter(
    int c, const bf16* __restrict__ Kp, const bf16* __restrict__ Vp,
    uint32_t (&vTu)[2][64][36],
    bf16x8 (&kf)[4][2], bf16x8 (&kfn)[4][2],
    const bf16x8& qf0, const bf16x8& qf1,
    f32x4 (&o)[4], float& mrun, float& lsum,
    int kp, int d0, int jperm, int g, int j)
{
    const f32x4 zero = {0.f, 0.f, 0.f, 0.f};
    const bool pf = (c + 1 < 16);

    u16x8 r0, r1;
    if (pf) {
        const size_t vb = (size_t)((c + 1) * 64 + kp) * 3072 + d0;
        r0 = *(const u16x8*)&Vp[vb];
        r1 = *(const u16x8*)&Vp[vb + 3072];
    }

    f32x4 s[4];
    #pragma unroll
    for (int t = 0; t < 4; ++t) {
        s[t] = __builtin_amdgcn_mfma_f32_16x16x32_bf16(kf[t][0], qf0, zero, 0, 0, 0);
        s[t] = __builtin_amdgcn_mfma_f32_16x16x32_bf16(kf[t][1], qf1, s[t], 0, 0, 0);
    }

    if (pf) {
        #pragma unroll
        for (int t = 0; t < 4; ++t) {
            const int key = (c + 1) * 64 + (t >> 1) * 32 + jperm + (t & 1) * 4;
            kfn[t][0] = *(const bf16x8*)&Kp[(size_t)key * 3072 + g * 8];
            kfn[t][1] = *(const bf16x8*)&Kp[(size_t)key * 3072 + 32 + g * 8];
        }
    }

    float cur = fmaxf(fmaxf(s[0][0], s[0][1]), fmaxf(s[0][2], s[0][3]));
    #pragma unroll
    for (int t = 1; t < 4; ++t)
        cur = fmaxf(cur, fmaxf(fmaxf(s[t][0], s[t][1]), fmaxf(s[t][2], s[t][3])));
    cur = fmaxf(cur, __shfl_xor(cur, 16));
    cur = fmaxf(cur, __shfl_xor(cur, 32));

    if (!__all(cur - mrun <= 8.0f)) {
        const float mnew = fmaxf(mrun, cur);
        const float alpha = __expf(mrun - mnew);
        float al[4];
        #pragma unroll
        for (int r = 0; r < 4; ++r) al[r] = __shfl(alpha, g * 4 + r);
        #pragma unroll
        for (int dt = 0; dt < 4; ++dt)
            #pragma unroll
            for (int r = 0; r < 4; ++r) o[dt][r] *= al[r];
        lsum *= alpha;
        mrun = mnew;
    }
    float ps = 0.f;
    #pragma unroll
    for (int t = 0; t < 4; ++t)
        #pragma unroll
        for (int r = 0; r < 4; ++r) {
            const float p = __expf(s[t][r] - mrun);
            s[t][r] = p;
            ps += p;
        }
    lsum += ps;

    bf16x8 pa0, pa1;
    #pragma unroll
    for (int r = 0; r < 4; ++r) {
        pa0[r]     = (bf16)s[0][r];
        pa0[4 + r] = (bf16)s[1][r];
        pa1[r]     = (bf16)s[2][r];
        pa1[4 + r] = (bf16)s[3][r];
    }

    if (pf) {
        #pragma unroll
        for (int i = 0; i < 8; ++i)
            vTu[(c + 1) & 1][d0 + i][kp >> 1] = (uint32_t)r0[i] | ((uint32_t)r1[i] << 16);
    }

    #pragma unroll
    for (int dt = 0; dt < 4; ++dt) {
        const bf16* vrow = (const bf16*)&vTu[c & 1][dt * 16 + j][0];
        const bf16x8 vb0 = *(const bf16x8*)(vrow + g * 8);
        const bf16x8 vb1 = *(const bf16x8*)(vrow + 32 + g * 8);
        o[dt] = __builtin_amdgcn_mfma_f32_16x16x32_bf16(pa0, vb0, o[dt], 0, 0, 0);
        o[dt] = __builtin_amdgcn_mfma_f32_16x16x32_bf16(pa1, vb1, o[dt], 0, 0, 0);
    }
    __syncthreads();
}

__global__ __launch_bounds__(256, 1) void attn_kernel(
    const bf16* __restrict__ qkv, bf16* __restrict__ attn, int bh_base)
{
    const int tid = threadIdx.x;
    const int lane = tid & 63, wid = tid >> 6;
    const int j = lane & 15, g = lane >> 4;

    const int lin = blockIdx.x + blockIdx.y * 16;
    const int virt = (lin & 7) * 128 + (lin >> 3);
    const int bh = bh_base + (virt >> 4), qt = virt & 15;
    const int b = bh >> 4, h = bh & 15;
    const int q0 = qt * 64 + wid * 16;

    const bf16* Qp = qkv + (size_t)b * 1024 * 3072 + h * 64;
    const bf16* Kp = Qp + 1024;
    const bf16* Vp = Qp + 2048;

    __shared__ __attribute__((aligned(16))) uint32_t vTu[2][64][36];

    const int kp = (tid & 31) * 2;
    const int d0 = (tid >> 5) * 8;
    {
        const u16x8 r0 = *(const u16x8*)&Vp[(size_t)kp * 3072 + d0];
        const u16x8 r1 = *(const u16x8*)&Vp[(size_t)(kp + 1) * 3072 + d0];
        #pragma unroll
        for (int i = 0; i < 8; ++i)
            vTu[0][d0 + i][kp >> 1] = (uint32_t)r0[i] | ((uint32_t)r1[i] << 16);
    }

    bf16x8 qf0 = *(const bf16x8*)&Qp[(size_t)(q0 + j) * 3072 + g * 8];
    bf16x8 qf1 = *(const bf16x8*)&Qp[(size_t)(q0 + j) * 3072 + 32 + g * 8];
    #pragma unroll
    for (int e = 0; e < 8; ++e) {
        qf0[e] = (bf16)((float)qf0[e] * 0.03125f);
        qf1[e] = (bf16)((float)qf1[e] * 0.03125f);
    }

    const int jperm = (j >> 2) * 8 + (j & 3);

    f32x4 o[4] = {};
    float mrun = -1e30f, lsum = 0.f;

    bf16x8 kfA[4][2], kfB[4][2];
    #pragma unroll
    for (int t = 0; t < 4; ++t) {
        const int key = (t >> 1) * 32 + jperm + (t & 1) * 4;
        kfA[t][0] = *(const bf16x8*)&Kp[(size_t)key * 3072 + g * 8];
        kfA[t][1] = *(const bf16x8*)&Kp[(size_t)key * 3072 + 32 + g * 8];
    }

    __syncthreads();

    for (int cc = 0; cc < 16; cc += 2) {
        attn_iter(cc,     Kp, Vp, vTu, kfA, kfB, qf0, qf1, o, mrun, lsum, kp, d0, jperm, g, j);
        attn_iter(cc + 1, Kp, Vp, vTu, kfB, kfA, qf0, qf1, o, mrun, lsum, kp, d0, jperm, g, j);
    }

    lsum += __shfl_xor(lsum, 16);
    lsum += __shfl_xor(lsum, 32);
    float inv[4];
    #pragma unroll
    for (int r = 0; r < 4; ++r) inv[r] = 1.0f / __shfl(lsum, g * 4 + r);
    #pragma unroll
    for (int dt = 0; dt < 4; ++dt)
        #pragma unroll
        for (int r = 0; r < 4; ++r)
            attn[(size_t)(b * 1024 + q0 + g * 4 + r) * 1024 + h * 64 + dt * 16 + j] =
                (bf16)(o[dt][r] * inv[r]);
}

// ---------------------------------------------------------------------------
extern "C" void kernel_launch(void* const* d_in, const int* in_sizes, int n_in,
                              void* d_out, int out_size, void* d_ws, size_t ws_size,
                              hipStream_t stream)
{
    const float* x    = (const float*)d_in[0];
    const float* ln1g = (const float*)d_in[1];
    const float* ln1b = (const float*)d_in[2];
    const float* wq   = (const float*)d_in[3];
    const float* bq   = (const float*)d_in[4];
    const float* wk   = (const float*)d_in[5];
    const float* bk   = (const float*)d_in[6];
    const float* wv   = (const float*)d_in[7];
    const float* bv   = (const float*)d_in[8];
    const float* wo   = (const float*)d_in[9];
    const float* bo   = (const float*)d_in[10];
    const float* ln2g = (const float*)d_in[11];
    const float* ln2b = (const float*)d_in[12];
    const float* w1   = (const float*)d_in[13];
    const float* b1   = (const float*)d_in[14];
    const float* w2   = (const float*)d_in[15];
    const float* b2   = (const float*)d_in[16];

    char* ws = (char*)d_ws;
    bf16* wqkvT = (bf16*)ws;  ws += (size_t)3072 * 1024 * 2;
    bf16* woT   = (bf16*)ws;  ws += (size_t)1024 * 1024 * 2;
    bf16* w1T   = (bf16*)ws;  ws += (size_t)4096 * 1024 * 2;
    bf16* w2T   = (bf16*)ws;  ws += (size_t)1024 * 4096 * 2;
    float* bqkv = (float*)ws; ws += (size_t)3072 * 4;
    bf16* h     = (bf16*)ws;  ws += (size_t)8192 * 1024 * 2;
    bf16* qkv   = (bf16*)ws;  ws += (size_t)8192 * 3072 * 2;
    bf16* attn  = (bf16*)ws;  ws += (size_t)8192 * 1024 * 2;
    float* outf = (float*)ws; ws += (size_t)8192 * 1024 * 4;
    bf16* m1    = (bf16*)ws;  ws += (size_t)8192 * 4096 * 2;

    (void)hipFuncSetAttribute((const void*)gemm_m201_kernel<0, 2>,
                              hipFuncAttributeMaxDynamicSharedMemorySize, 131072);
    (void)hipFuncSetAttribute((const void*)gemm_m201_kernel<2, 2>,
                              hipFuncAttributeMaxDynamicSharedMemorySize, 131072);
    (void)hipFuncSetAttribute((const void*)gemm_m201_kernel<1, 1>,
                              hipFuncAttributeMaxDynamicSharedMemorySize, 98304);
    (void)hipFuncSetAttribute((const void*)gemm_m201_kernel<3, 1>,
                              hipFuncAttributeMaxDynamicSharedMemorySize, 98304);

    wtrans_kernel<<<dim3(16, 16), 256, 0, stream>>>(wq, wqkvT,                   1024, 1024);
    wtrans_kernel<<<dim3(16, 16), 256, 0, stream>>>(wk, wqkvT + 1024 * 1024,     1024, 1024);
    wtrans_kernel<<<dim3(16, 16), 256, 0, stream>>>(wv, wqkvT + 2 * 1024 * 1024, 1024, 1024);
    wtrans_kernel<<<dim3(16, 16), 256, 0, stream>>>(wo, woT, 1024, 1024);
    wtrans_kernel<<<dim3(64, 16), 256, 0, stream>>>(w1, w1T, 1024, 4096);
    wtrans_kernel<<<dim3(16, 64), 256, 0, stream>>>(w2, w2T, 4096, 1024);
    bias3_kernel<<<12, 256, 0, stream>>>(bq, bk, bv, bqkv);

    // LN1
    ln_kernel<<<8192, 256, 0, stream>>>(x, ln1g, ln1b, h);
    // QKV projection: 32x12 = 384 blocks (WM=2)
    gemm_m201_kernel<0, 2><<<384, 512, 131072, stream>>>(h, wqkvT, bqkv, nullptr, qkv, 8192, 3072, 1024);
    // attention (2 dispatches for profiler visibility)
    attn_kernel<<<dim3(16, 64), 256, 0, stream>>>(qkv, attn, 0);
    attn_kernel<<<dim3(16, 64), 256, 0, stream>>>(qkv, attn, 64);
    // O projection + bias + residual(x): 64x4 = 256 blocks (WM=1)
    gemm_m201_kernel<1, 1><<<256, 256, 98304, stream>>>(attn, woT, bo, x, outf, 8192, 1024, 1024);
    // LN2
    ln_kernel<<<8192, 256, 0, stream>>>(outf, ln2g, ln2b, h);
    // MLP1: 32x16 = 512 blocks (WM=2)
    gemm_m201_kernel<2, 2><<<512, 512, 131072, stream>>>(h, w1T, b1, nullptr, m1, 8192, 4096, 1024);
    // MLP2: 64x4 = 256 blocks (WM=1), K=4096
    gemm_m201_kernel<3, 1><<<256, 256, 98304, stream>>>(m1, w2T, b2, outf, (float*)d_out, 8192, 1024, 4096);
}